// Round 20
// baseline (188.292 us; speedup 1.0000x reference)
//
#include <hip/hip_runtime.h>
#include <math.h>

// ---------------------------------------------------------------------------
// SimGNN forward on MI355X (gfx950).  R19 = R17 +
//   fusedB gemm3 via MFMA (W3t bf16, same layout as fusedA's proven gemms)
//   SIM_CHUNK 2->4 with 8-bit pack flushed to 16-bit every 2 tiles
// ---------------------------------------------------------------------------

#define SIM_CHUNK 4
#define GS_PAD 16
#define GS_REP 8

using bf16x8 = __attribute__((ext_vector_type(8))) short;
using f32x4  = __attribute__((ext_vector_type(4))) float;

__device__ __forceinline__ unsigned short f2bf(float f) {  // RNE
    unsigned u = __float_as_uint(f);
    unsigned r = ((u >> 16) & 1u) + 0x7FFFu;
    return (unsigned short)((u + r) >> 16);
}
__device__ __forceinline__ void bf4_load(const unsigned short* __restrict__ p,
                                         float f[4]) {
    uint2 u = *(const uint2*)p;
    f[0] = __uint_as_float(u.x << 16);
    f[1] = __uint_as_float(u.x & 0xFFFF0000u);
    f[2] = __uint_as_float(u.y << 16);
    f[3] = __uint_as_float(u.y & 0xFFFF0000u);
}
__device__ __forceinline__ uint2 bf4_pack(float a, float b, float c, float d) {
    uint2 u;
    u.x = (unsigned)f2bf(a) | ((unsigned)f2bf(b) << 16);
    u.y = (unsigned)f2bf(c) | ((unsigned)f2bf(d) << 16);
    return u;
}

// ---- bf16 prescaled gather: returns h'[r] + sum_s h'[s] (f32 accum) ----
template <int F>
__device__ __forceinline__ float4 aggRowBF(const unsigned short* __restrict__ hp,
                                           const int* __restrict__ offs,
                                           const int* __restrict__ esrc,
                                           int r, int fq) {
    float f[4];
    bf4_load(&hp[(size_t)r * F + fq], f);
    float ax = f[0], ay = f[1], az = f[2], aw = f[3];
    int e = offs[r], e1 = offs[r + 1];
    for (; e + 4 <= e1; e += 4) {
        int s0 = esrc[e], s1 = esrc[e + 1], s2 = esrc[e + 2], s3 = esrc[e + 3];
        float f0[4], f1[4], f2[4], f3[4];
        bf4_load(&hp[(size_t)s0 * F + fq], f0);
        bf4_load(&hp[(size_t)s1 * F + fq], f1);
        bf4_load(&hp[(size_t)s2 * F + fq], f2);
        bf4_load(&hp[(size_t)s3 * F + fq], f3);
        ax += f0[0] + f1[0]; ay += f0[1] + f1[1];
        az += f0[2] + f1[2]; aw += f0[3] + f1[3];
        ax += f2[0] + f3[0]; ay += f2[1] + f3[1];
        az += f2[2] + f3[2]; aw += f2[3] + f3[3];
    }
    for (; e < e1; ++e) {
        int s = esrc[e];
        float fs[4];
        bf4_load(&hp[(size_t)s * F + fq], fs);
        ax += fs[0]; ay += fs[1]; az += fs[2]; aw += fs[3];
    }
    return make_float4(ax, ay, az, aw);
}

// ========= zero_prep: zero gsum|p12|cnt + transpose W1,W2,W3 to bf16 =======
__global__ void zero_prep(float4* __restrict__ p, int n4,
                          const float* __restrict__ W1, const float* __restrict__ W2,
                          const float* __restrict__ W3,
                          unsigned short* __restrict__ W1t,
                          unsigned short* __restrict__ W2t,
                          unsigned short* __restrict__ W3t) {
    int nzb = gridDim.x - 3;
    int b = blockIdx.x;
    if (b < nzb) {
        int i = b * 256 + threadIdx.x;
        if (i < n4) p[i] = make_float4(0.f, 0.f, 0.f, 0.f);
        return;
    }
    if (b == nzb) {        // W1t[c][k] = bf16(W1[k][c]), c<128, k<64
        for (int i = threadIdx.x; i < 128 * 64; i += 256) {
            int c = i >> 6, k = i & 63;
            W1t[c * 64 + k] = f2bf(W1[k * 128 + c]);
        }
    } else if (b == nzb + 1) {  // W2t[c][k] = bf16(W2[k][c]), c<64, k<128
        for (int i = threadIdx.x; i < 64 * 128; i += 256) {
            int c = i >> 7, k = i & 127;
            W2t[c * 128 + k] = f2bf(W2[k * 64 + c]);
        }
    } else {               // W3t[c][k] = bf16(W3[k][c]), c<32, k<64
        for (int i = threadIdx.x; i < 32 * 64; i += 256) {
            int c = i >> 6, k = i & 63;
            W3t[c * 64 + k] = f2bf(W3[k * 32 + c]);
        }
    }
}

__global__ void count_tgt(const int* __restrict__ t0, const int* __restrict__ t1,
                          int* __restrict__ cnt, int N, int E) {
    int g = blockIdx.y;
    const int* t = g ? t1 : t0;
    int i = blockIdx.x * 256 + threadIdx.x;
    if (i < E) atomicAdd(&cnt[g * N + t[i]], 1);
}

// ========= scan_xscale: blocks 0,1 = scan; rest = xscale ====================
__global__ __launch_bounds__(1024) void scan_xscale(const int* __restrict__ cnt_,
                                                    int* __restrict__ offs_,
                                                    int* __restrict__ cursor_,
                                                    float* __restrict__ dinv_,
                                                    const float* __restrict__ x1,
                                                    const float* __restrict__ x2,
                                                    unsigned short* __restrict__ xs,
                                                    int N) {
    int b = blockIdx.x;
    if (b < 2) {
        int g = b;
        const int* cnt = cnt_ + g * N;
        int* offs = offs_ + g * (N + 1);
        int* cursor = cursor_ + g * N;
        float* dinv = dinv_ + g * N;
        int tid = threadIdx.x, lane = tid & 63, wid = tid >> 6;
        int chunk = (N + 1023) >> 10;
        int base = tid * chunk;
        int s = 0;
        for (int i = 0; i < chunk; ++i) {
            int idx = base + i;
            if (idx < N) s += cnt[idx];
        }
        int v = s;
#pragma unroll
        for (int d = 1; d < 64; d <<= 1) {
            int u = __shfl_up(v, d);
            if (lane >= d) v += u;
        }
        __shared__ int wtot[16], wbase[16];
        if (lane == 63) wtot[wid] = v;
        __syncthreads();
        if (tid == 0) {
            int r = 0;
            for (int i = 0; i < 16; ++i) { wbase[i] = r; r += wtot[i]; }
            offs[N] = r;
        }
        __syncthreads();
        int run = wbase[wid] + (v - s);
        for (int i = 0; i < chunk; ++i) {
            int idx = base + i;
            if (idx < N) {
                int c = cnt[idx];
                offs[idx] = run;
                cursor[idx] = run;
                dinv[idx] = 1.0f / sqrtf((float)(c + 1));
                run += c;
            }
        }
        return;
    }
    int i = (b - 2) * 1024 + threadIdx.x;
    if (i >= 2 * N * 16) return;
    int row = i >> 4;
    int g = row >= N;
    const float* x = g ? x2 : x1;
    int r = row - (g ? N : 0);
    float4 v = ((const float4*)x)[(size_t)r * 16 + (i & 15)];
    float d = 1.0f / sqrtf((float)(cnt_[row] + 1));
    ((uint2*)xs)[i] = bf4_pack(d * v.x, d * v.y, d * v.z, d * v.w);
}

__global__ void scatter_src(const int* __restrict__ s0, const int* __restrict__ s1,
                            const int* __restrict__ t0, const int* __restrict__ t1,
                            int* __restrict__ cursor, int* __restrict__ esrc, int N, int E) {
    int g = blockIdx.y;
    const int* src = g ? s1 : s0;
    const int* tgt = g ? t1 : t0;
    int i = blockIdx.x * 256 + threadIdx.x;
    if (i < E) {
        int t = tgt[i];
        int pos = atomicAdd(&cursor[g * N + t], 1);
        esrc[g * E + pos] = src[i];
    }
}

// ========= fusedA: agg1(xs) -> MFMA gemm1(+b1,relu) -> MFMA gemm2 -> t1' ====
__global__ __launch_bounds__(256) void fusedA(const unsigned short* __restrict__ xs,
                                              const unsigned short* __restrict__ W1t,
                                              const float* __restrict__ b1,
                                              const unsigned short* __restrict__ W2t,
                                              unsigned short* __restrict__ t1,
                                              const int* __restrict__ offs_,
                                              const int* __restrict__ esrc_,
                                              const float* __restrict__ dinv_,
                                              int N, int E) {
    __shared__ unsigned short Xb[16][72];
    __shared__ unsigned short H1b[16][136];
    __shared__ float dtl[16];
    int g = blockIdx.y;
    const unsigned short* xp = xs + (size_t)(g ? N : 0) * 64;
    const int* offs = offs_ + g * (N + 1);
    const int* esrc = esrc_ + (size_t)g * E;
    const float* dinv = dinv_ + g * N;
    int rb = blockIdx.x * 16;
    int tid = threadIdx.x;
    int tc = tid & 15, tr = tid >> 4;
    if (tid < 16) dtl[tid] = dinv[rb + tid];
    {
        float dt_row = dinv[rb + tr];
        int fq = tc * 4;
        float4 v = aggRowBF<64>(xp, offs, esrc, rb + tr, fq);
        *(uint2*)&Xb[tr][fq] =
            bf4_pack(dt_row * v.x, dt_row * v.y, dt_row * v.z, dt_row * v.w);
    }
    __syncthreads();

    int lane = tid & 63, wv = tid >> 6;
    int lr = lane & 15;
    int kg = (lane >> 4) << 3;

    bf16x8 a0 = *(const bf16x8*)&Xb[lr][kg];
    bf16x8 a1 = *(const bf16x8*)&Xb[lr][32 + kg];

    f32x4 zero = {0.f, 0.f, 0.f, 0.f};
#pragma unroll
    for (int t = 0; t < 2; ++t) {
        int ct = wv + t * 4;
        const unsigned short* wb = W1t + (size_t)(ct * 16 + lr) * 64;
        bf16x8 b0 = *(const bf16x8*)&wb[kg];
        bf16x8 b1f = *(const bf16x8*)&wb[32 + kg];
        f32x4 acc = __builtin_amdgcn_mfma_f32_16x16x32_bf16(a0, b0, zero, 0, 0, 0);
        acc = __builtin_amdgcn_mfma_f32_16x16x32_bf16(a1, b1f, acc, 0, 0, 0);
        int col = ct * 16 + lr;
        float bias = b1[col];
#pragma unroll
        for (int r = 0; r < 4; ++r) {
            int row = (lane >> 4) * 4 + r;
            float v = fmaxf(acc[r] + bias, 0.f);
            H1b[row][col] = f2bf(v);
        }
    }
    __syncthreads();
    {
        int ct = wv;
        const unsigned short* wb = W2t + (size_t)(ct * 16 + lr) * 128;
        f32x4 acc = zero;
#pragma unroll
        for (int kb = 0; kb < 4; ++kb) {
            bf16x8 af = *(const bf16x8*)&H1b[lr][kb * 32 + kg];
            bf16x8 bf = *(const bf16x8*)&wb[kb * 32 + kg];
            acc = __builtin_amdgcn_mfma_f32_16x16x32_bf16(af, bf, acc, 0, 0, 0);
        }
        int col = ct * 16 + lr;
        size_t gbase = (size_t)(g ? N : 0) + rb;
#pragma unroll
        for (int r = 0; r < 4; ++r) {
            int row = (lane >> 4) * 4 + r;
            t1[(gbase + row) * 64 + col] = f2bf(dtl[row] * acc[r]);
        }
    }
}

// ========= fusedB: agg2(t1',+b2,relu) -> MFMA gemm3(W3t) -> t3' (bf16) ======
__global__ __launch_bounds__(256) void fusedB(const unsigned short* __restrict__ t1,
                                              const float* __restrict__ b2,
                                              const unsigned short* __restrict__ W3t,
                                              unsigned short* __restrict__ t3,
                                              const int* __restrict__ offs_,
                                              const int* __restrict__ esrc_,
                                              const float* __restrict__ dinv_,
                                              int N, int E) {
    __shared__ unsigned short Xb[16][72];
    __shared__ float dtl[16];
    int g = blockIdx.y;
    const unsigned short* hp = t1 + (size_t)(g ? N : 0) * 64;
    const int* offs = offs_ + g * (N + 1);
    const int* esrc = esrc_ + (size_t)g * E;
    const float* dinv = dinv_ + g * N;
    int rb = blockIdx.x * 16;
    int tid = threadIdx.x;
    int tc = tid & 15, tr = tid >> 4;
    if (tid < 16) dtl[tid] = dinv[rb + tid];
    {
        float dt_row = dinv[rb + tr];
        int fq = tc * 4;
        float4 bb = *(const float4*)&b2[fq];
        float4 v = aggRowBF<64>(hp, offs, esrc, rb + tr, fq);
        v.x = fmaxf(fmaf(dt_row, v.x, bb.x), 0.f);
        v.y = fmaxf(fmaf(dt_row, v.y, bb.y), 0.f);
        v.z = fmaxf(fmaf(dt_row, v.z, bb.z), 0.f);
        v.w = fmaxf(fmaf(dt_row, v.w, bb.w), 0.f);
        *(uint2*)&Xb[tr][fq] = bf4_pack(v.x, v.y, v.z, v.w);
    }
    __syncthreads();
    int lane = tid & 63, wv = tid >> 6;
    if (wv < 2) {  // gemm3: X(16x64) @ W3(64x32); wave wv -> col-tile wv
        int lr = lane & 15;
        int kg = (lane >> 4) << 3;
        bf16x8 a0 = *(const bf16x8*)&Xb[lr][kg];
        bf16x8 a1 = *(const bf16x8*)&Xb[lr][32 + kg];
        const unsigned short* wb = W3t + (size_t)(wv * 16 + lr) * 64;
        bf16x8 b0 = *(const bf16x8*)&wb[kg];
        bf16x8 b1f = *(const bf16x8*)&wb[32 + kg];
        f32x4 zero = {0.f, 0.f, 0.f, 0.f};
        f32x4 acc = __builtin_amdgcn_mfma_f32_16x16x32_bf16(a0, b0, zero, 0, 0, 0);
        acc = __builtin_amdgcn_mfma_f32_16x16x32_bf16(a1, b1f, acc, 0, 0, 0);
        int col = wv * 16 + lr;
        size_t gbase = (size_t)(g ? N : 0) + rb;
#pragma unroll
        for (int r = 0; r < 4; ++r) {
            int row = (lane >> 4) * 4 + r;
            t3[(gbase + row) * 32 + col] = f2bf(dtl[row] * acc[r]);
        }
    }
}

// ========= agg3 + pool (gsum) + bf16 mirror ================================
__global__ __launch_bounds__(256) void agg3_pool(const unsigned short* __restrict__ t3,
                                                 const int* __restrict__ offs_,
                                                 const int* __restrict__ esrc_,
                                                 const float* __restrict__ dinv_,
                                                 const float* __restrict__ b,
                                                 float* __restrict__ out,
                                                 unsigned short* __restrict__ outbf,
                                                 float* __restrict__ gsum, int N, int E) {
    int g = blockIdx.y;
    const unsigned short* hp = t3 + (size_t)(g ? N : 0) * 32;
    const int* offs = offs_ + g * (N + 1);
    const int* esrc = esrc_ + (size_t)g * E;
    const float* dinv = dinv_ + g * N;
    int fq = (threadIdx.x & 7) * 4;
    int t = blockIdx.x * 32 + threadIdx.x / 8;
    float dt_row = dinv[t];
    float4 v = aggRowBF<32>(hp, offs, esrc, t, fq);
    float4 bb = *(const float4*)&b[fq];
    v.x = fmaf(dt_row, v.x, bb.x); v.y = fmaf(dt_row, v.y, bb.y);
    v.z = fmaf(dt_row, v.z, bb.z); v.w = fmaf(dt_row, v.w, bb.w);
    *(float4*)&out[((size_t)(g * N + t)) * 32 + fq] = v;
    unsigned short r4[4] = {f2bf(v.x), f2bf(v.y), f2bf(v.z), f2bf(v.w)};
    *(uint2*)&outbf[((size_t)(g * N + t)) * 32 + fq] = *(uint2*)r4;
    __shared__ float ls[32];
    if (threadIdx.x < 32) ls[threadIdx.x] = 0.f;
    __syncthreads();
    atomicAdd(&ls[fq + 0], v.x);
    atomicAdd(&ls[fq + 1], v.y);
    atomicAdd(&ls[fq + 2], v.z);
    atomicAdd(&ls[fq + 3], v.w);
    __syncthreads();
    if (threadIdx.x < 32) {
        int rep = blockIdx.x & (GS_REP - 1);
        atomicAdd(&gsum[((g * GS_REP + rep) * 32 + threadIdx.x) * GS_PAD],
                  ls[threadIdx.x]);
    }
}

// ========= simA: sim min/max (blocks < NSIM) + attention pool (rest) ========
__global__ __launch_bounds__(256) void simA(const unsigned short* __restrict__ afbf,
                                            const float* __restrict__ af,
                                            const float* __restrict__ gsum,
                                            const float* __restrict__ Wa,
                                            float* __restrict__ p12,
                                            float2* __restrict__ pbmm, int N, int NSIM) {
    int bid = blockIdx.x;
    int tid = threadIdx.x;
    int lane = tid & 63, wv = tid >> 6;
    if (bid >= NSIM) {
        int pb = bid - NSIM;
        int npg = N / 256;
        int g = pb / npg;
        int r = (pb % npg) * 256 + tid;
        const float* afg = af + (size_t)g * N * 32;
        __shared__ float cm[32], ctxs[32];
        if (tid < 32) {
            float s = 0.f;
#pragma unroll
            for (int rep = 0; rep < GS_REP; ++rep)
                s += gsum[((g * GS_REP + rep) * 32 + tid) * GS_PAD];
            cm[tid] = s / (float)N;
        }
        __syncthreads();
        if (tid < 32) {
            float s = 0.f;
            for (int d = 0; d < 32; ++d) s = fmaf(cm[d], Wa[d * 32 + tid], s);
            ctxs[tid] = tanhf(s);
        }
        __syncthreads();
        float rowv[32];
        const float4* row = (const float4*)(afg + (size_t)r * 32);
        float dot = 0.f;
#pragma unroll
        for (int q = 0; q < 8; ++q) {
            float4 v = row[q];
            rowv[q * 4 + 0] = v.x; rowv[q * 4 + 1] = v.y;
            rowv[q * 4 + 2] = v.z; rowv[q * 4 + 3] = v.w;
            dot = fmaf(v.x, ctxs[q * 4 + 0], dot);
            dot = fmaf(v.y, ctxs[q * 4 + 1], dot);
            dot = fmaf(v.z, ctxs[q * 4 + 2], dot);
            dot = fmaf(v.w, ctxs[q * 4 + 3], dot);
        }
        float att = 1.f / (1.f + expf(-dot));
        __shared__ float wsum[4][32];
#pragma unroll
        for (int f = 0; f < 32; ++f) {
            float v = att * rowv[f];
#pragma unroll
            for (int off = 1; off < 64; off <<= 1) v += __shfl_xor(v, off);
            if (lane == 0) wsum[wv][f] = v;
        }
        __syncthreads();
        if (tid < 32) {
            float s = wsum[0][tid] + wsum[1][tid] + wsum[2][tid] + wsum[3][tid];
            atomicAdd(&p12[g * 32 + tid], s);
        }
        return;
    }
    const unsigned short* a1 = afbf;
    const unsigned short* a2 = afbf + (size_t)N * 32;
    int nb = N >> 7;
    int nchunk = nb / SIM_CHUNK;
    int by = bid / nchunk;
    int ch = bid % nchunk;
    int r16 = lane & 15, kg = (lane >> 4) << 3;
    const unsigned short* arow = a1 + ((size_t)(by * 128 + (wv >> 1) * 64 + r16)) * 32 + kg;
    bf16x8 afr[4];
#pragma unroll
    for (int m = 0; m < 4; ++m) afr[m] = *(const bf16x8*)(arow + m * 16 * 32);
    float mn = 1e30f, mx = -1e30f;
#pragma unroll
    for (int t = 0; t < SIM_CHUNK; ++t) {
        int bx = ch * SIM_CHUNK + t;
        const unsigned short* brow =
            a2 + ((size_t)(bx * 128 + (wv & 1) * 64 + r16)) * 32 + kg;
        bf16x8 bfr[4];
#pragma unroll
        for (int n = 0; n < 4; ++n) bfr[n] = *(const bf16x8*)(brow + n * 16 * 32);
        f32x4 zero = {0.f, 0.f, 0.f, 0.f};
        f32x4 acc[4][4];
#pragma unroll
        for (int m = 0; m < 4; ++m)
#pragma unroll
            for (int n = 0; n < 4; ++n)
                acc[m][n] =
                    __builtin_amdgcn_mfma_f32_16x16x32_bf16(afr[m], bfr[n], zero, 0, 0, 0);
#pragma unroll
        for (int m = 0; m < 4; ++m)
#pragma unroll
            for (int n = 0; n < 4; ++n)
#pragma unroll
                for (int e = 0; e < 4; ++e) {
                    float v = acc[m][n][e];
                    mn = fminf(mn, v);
                    mx = fmaxf(mx, v);
                }
    }
#pragma unroll
    for (int off = 1; off < 64; off <<= 1) {
        mn = fminf(mn, __shfl_xor(mn, off));
        mx = fmaxf(mx, __shfl_xor(mx, off));
    }
    __shared__ float wmn[4], wmx[4];
    if (lane == 0) { wmn[wv] = mn; wmx[wv] = mx; }
    __syncthreads();
    if (tid == 0) {
        float bmn = fminf(fminf(wmn[0], wmn[1]), fminf(wmn[2], wmn[3]));
        float bmx = fmaxf(fmaxf(wmx[0], wmx[1]), fmaxf(wmx[2], wmx[3]));
        pbmm[bid] = make_float2(bmn, bmx);
    }
}

// ========= simB: histogram (pack 8-bit, flush to 16-bit every 2 tiles) ======
__global__ __launch_bounds__(256) void simB(const unsigned short* __restrict__ a1,
                                            const unsigned short* __restrict__ a2,
                                            int N, int nblk,
                                            const float2* __restrict__ pbmm,
                                            unsigned* __restrict__ pbhist) {
    int nb = N >> 7;
    int nchunk = nb / SIM_CHUNK;
    int by = blockIdx.x / nchunk;
    int ch = blockIdx.x % nchunk;
    int w = threadIdx.x >> 6, lane = threadIdx.x & 63;
    int r16 = lane & 15, kg = (lane >> 4) << 3;
    __shared__ unsigned hs[16];
    __shared__ float mnmx[2];
    if (threadIdx.x < 16) hs[threadIdx.x] = 0;
    {
        float mn2 = 1e30f, mx2 = -1e30f;
        for (int i = threadIdx.x; i < nblk; i += 256) {
            float2 vv = pbmm[i];
            mn2 = fminf(mn2, vv.x);
            mx2 = fmaxf(mx2, vv.y);
        }
#pragma unroll
        for (int off = 1; off < 64; off <<= 1) {
            mn2 = fminf(mn2, __shfl_xor(mn2, off));
            mx2 = fmaxf(mx2, __shfl_xor(mx2, off));
        }
        __shared__ float wmn2[4], wmx2[4];
        if (lane == 0) { wmn2[w] = mn2; wmx2[w] = mx2; }
        __syncthreads();
        if (threadIdx.x == 0) {
            mnmx[0] = fminf(fminf(wmn2[0], wmn2[1]), fminf(wmn2[2], wmn2[3]));
            mnmx[1] = fmaxf(fmaxf(wmx2[0], wmx2[1]), fmaxf(wmx2[2], wmx2[3]));
        }
        __syncthreads();
    }
    float mnv = mnmx[0], mxv = mnmx[1];
    float width = (mxv > mnv) ? (mxv - mnv) : 1.0f;
    float scale = 16.0f / width;
    float nbias = -mnv * scale;
    const unsigned short* arow = a1 + ((size_t)(by * 128 + (w >> 1) * 64 + r16)) * 32 + kg;
    bf16x8 afr[4];
#pragma unroll
    for (int m = 0; m < 4; ++m) afr[m] = *(const bf16x8*)(arow + m * 16 * 32);
    unsigned hh[8] = {0u, 0u, 0u, 0u, 0u, 0u, 0u, 0u};
#pragma unroll
    for (int half = 0; half < SIM_CHUNK / 2; ++half) {
        unsigned h4_0 = 0, h4_1 = 0, h4_2 = 0, h4_3 = 0;
#pragma unroll
        for (int t = 0; t < 2; ++t) {
            int bx = ch * SIM_CHUNK + half * 2 + t;
            const unsigned short* brow =
                a2 + ((size_t)(bx * 128 + (w & 1) * 64 + r16)) * 32 + kg;
            bf16x8 bfr[4];
#pragma unroll
            for (int n = 0; n < 4; ++n) bfr[n] = *(const bf16x8*)(brow + n * 16 * 32);
            f32x4 zero = {0.f, 0.f, 0.f, 0.f};
            f32x4 acc[4][4];
#pragma unroll
            for (int m = 0; m < 4; ++m)
#pragma unroll
                for (int n = 0; n < 4; ++n)
                    acc[m][n] = __builtin_amdgcn_mfma_f32_16x16x32_bf16(afr[m], bfr[n],
                                                                        zero, 0, 0, 0);
#pragma unroll
            for (int m = 0; m < 4; ++m)
#pragma unroll
                for (int n = 0; n < 4; ++n)
#pragma unroll
                    for (int e = 0; e < 4; ++e) {
                        float v = acc[m][n][e];
                        int bin = (int)fmaf(v, scale, nbias);
                        bin = bin < 0 ? 0 : (bin > 15 ? 15 : bin);
                        unsigned wbit = 1u << ((bin & 3) << 3);
                        int hi = bin >> 2;
                        h4_0 += (hi == 0) ? wbit : 0u;
                        h4_1 += (hi == 1) ? wbit : 0u;
                        h4_2 += (hi == 2) ? wbit : 0u;
                        h4_3 += (hi == 3) ? wbit : 0u;
                    }
        }
        // flush 8-bit packs (max 128/bin) into 16-bit accumulators
        hh[0] += h4_0 & 0x00FF00FFu; hh[1] += (h4_0 >> 8) & 0x00FF00FFu;
        hh[2] += h4_1 & 0x00FF00FFu; hh[3] += (h4_1 >> 8) & 0x00FF00FFu;
        hh[4] += h4_2 & 0x00FF00FFu; hh[5] += (h4_2 >> 8) & 0x00FF00FFu;
        hh[6] += h4_3 & 0x00FF00FFu; hh[7] += (h4_3 >> 8) & 0x00FF00FFu;
    }
#pragma unroll
    for (int off = 1; off < 64; off <<= 1) {
#pragma unroll
        for (int q = 0; q < 8; ++q) hh[q] += (unsigned)__shfl_xor((int)hh[q], off);
    }
    __syncthreads();
    if (lane < 16) {
        int q = lane >> 2, r = lane & 3;
        unsigned word = hh[2 * q + (r & 1)];
        unsigned val = (r < 2) ? (word & 0xFFFFu) : (word >> 16);
        atomicAdd(&hs[lane], val);
    }
    __syncthreads();
    if (threadIdx.x < 16)
        pbhist[(size_t)blockIdx.x * 16 + threadIdx.x] = hs[threadIdx.x];
}

// ========= hist reduce + NTN + MLP head ====================================
__global__ __launch_bounds__(256) void ntn_final(
    const float* __restrict__ p12, const float* __restrict__ Wt,
    const float* __restrict__ V, const float* __restrict__ bt,
    const unsigned* __restrict__ pbhist, int nblk,
    const float* __restrict__ fc1W, const float* __restrict__ fc1b,
    const float* __restrict__ fc2W, const float* __restrict__ fc2b,
    const float* __restrict__ fc3W, const float* __restrict__ fc3b,
    const float* __restrict__ scW, const float* __restrict__ scb,
    const float* __restrict__ avg_v, float* __restrict__ out) {
    __shared__ float p1l[32], p2l[32];
    __shared__ float scp[16][17];
    __shared__ unsigned hs[16];
    __shared__ float sc[16];
    __shared__ float sfeat[32];
    __shared__ float h1s[16];
    int t = threadIdx.x;
    if (t < 16) hs[t] = 0;
    if (t < 32) p1l[t] = p12[t];
    else if (t < 64) p2l[t - 32] = p12[t];
    __syncthreads();
    {
        const uint4* pb = (const uint4*)pbhist;
        int total = nblk * 4;
        uint4 a = {0u, 0u, 0u, 0u};
        for (int i = t; i < total; i += 256) {
            uint4 v = pb[i];
            a.x += v.x; a.y += v.y; a.z += v.z; a.w += v.w;
        }
#pragma unroll
        for (int off = 4; off < 64; off <<= 1) {
            a.x += (unsigned)__shfl_xor((int)a.x, off);
            a.y += (unsigned)__shfl_xor((int)a.y, off);
            a.z += (unsigned)__shfl_xor((int)a.z, off);
            a.w += (unsigned)__shfl_xor((int)a.w, off);
        }
        int lane = t & 63;
        if (lane < 4) {
            atomicAdd(&hs[lane * 4 + 0], a.x);
            atomicAdd(&hs[lane * 4 + 1], a.y);
            atomicAdd(&hs[lane * 4 + 2], a.z);
            atomicAdd(&hs[lane * 4 + 3], a.w);
        }
    }
    {
        int k = t & 15, dp = t >> 4;
        float s = 0.f;
#pragma unroll
        for (int dd = 0; dd < 2; ++dd) {
            int d = dp * 2 + dd;
            float a = p1l[d];
            for (int e = 0; e < 32; ++e)
                s = fmaf(a * p2l[e], Wt[(d * 32 + e) * 16 + k], s);
        }
        scp[dp][k] = s;
    }
    __syncthreads();
    if (t < 16) {
        float s = 0.f;
#pragma unroll
        for (int dp = 0; dp < 16; ++dp) s += scp[dp][t];
        float bl = 0.f;
        for (int m = 0; m < 32; ++m) bl = fmaf(V[t * 64 + m], p1l[m], bl);
        for (int m = 0; m < 32; ++m) bl = fmaf(V[t * 64 + 32 + m], p2l[m], bl);
        sc[t] = fmaxf(s + bl + bt[t], 0.f);
    }
    __syncthreads();
    if (t < 16) sfeat[t] = sc[t];
    if (t == 16) {
        unsigned tot = 0;
        for (int b = 0; b < 16; ++b) tot += hs[b];
        float ftot = (float)tot;
        for (int b = 0; b < 16; ++b) sfeat[16 + b] = (float)hs[b] / ftot;
    }
    __syncthreads();
    if (t < 16) {
        float a = fc1b[t];
        for (int m = 0; m < 32; ++m) a = fmaf(sfeat[m], fc1W[m * 16 + t], a);
        h1s[t] = fmaxf(a, 0.f);
    }
    __syncthreads();
    if (t != 0) return;
    float h2[8];
    for (int r = 0; r < 8; ++r) {
        float a = fc2b[r];
        for (int m = 0; m < 16; ++m) a = fmaf(h1s[m], fc2W[m * 8 + r], a);
        h2[r] = fmaxf(a, 0.f);
    }
    float h3[4];
    for (int r = 0; r < 4; ++r) {
        float a = fc3b[r];
        for (int m = 0; m < 8; ++m) a = fmaf(h2[m], fc3W[m * 4 + r], a);
        h3[r] = fmaxf(a, 0.f);
    }
    float z = scb[0];
    for (int m = 0; m < 4; ++m) z = fmaf(h3[m], scW[m], z);
    float sig = 1.f / (1.f + expf(-z));
    out[0] = sig;
    out[1] = -logf(sig) * avg_v[0];
}

// ---------------------------------------------------------------------------
extern "C" void kernel_launch(void* const* d_in, const int* in_sizes, int n_in,
                              void* d_out, int out_size, void* d_ws, size_t ws_size,
                              hipStream_t stream) {
    (void)n_in; (void)out_size; (void)ws_size;
    const int* ei1 = (const int*)d_in[0];
    const int* ei2 = (const int*)d_in[1];
    const float* feat1 = (const float*)d_in[2];
    const float* feat2 = (const float*)d_in[3];
    const float* avg_v = (const float*)d_in[4];
    const float* W1 = (const float*)d_in[5];
    const float* b1 = (const float*)d_in[6];
    const float* W2 = (const float*)d_in[7];
    const float* b2 = (const float*)d_in[8];
    const float* W3 = (const float*)d_in[9];
    const float* b3 = (const float*)d_in[10];
    const float* Wa = (const float*)d_in[11];
    const float* Wt = (const float*)d_in[12];
    const float* V = (const float*)d_in[13];
    const float* bt = (const float*)d_in[14];
    const float* fc1W = (const float*)d_in[15];
    const float* fc1b = (const float*)d_in[16];
    const float* fc2W = (const float*)d_in[17];
    const float* fc2b = (const float*)d_in[18];
    const float* fc3W = (const float*)d_in[19];
    const float* fc3b = (const float*)d_in[20];
    const float* scW = (const float*)d_in[21];
    const float* scb = (const float*)d_in[22];

    const int E = in_sizes[0] / 2;
    const int N = in_sizes[2] / 64;
    const int nb = N / 128;
    const int nchunk = nb / SIM_CHUNK;
    const int NSIM = nb * nchunk;

    // ---- workspace layout ----
    char* w = (char*)d_ws;
    size_t off = 0;
    auto take = [&](size_t bytes) -> char* {
        char* p = w + off;
        off = (off + bytes + 255) & ~(size_t)255;
        return p;
    };
    float* gsum = (float*)take((size_t)2 * GS_REP * 32 * GS_PAD * 4);  // zero start
    float* p12 = (float*)take(64 * 4);
    int* cnt = (int*)take((size_t)2 * N * 4);                          // zero end
    float* af = (float*)take((size_t)2 * N * 32 * 4);
    unsigned short* afbf = (unsigned short*)take((size_t)2 * N * 32 * 2);
    float2* pbmm = (float2*)take((size_t)NSIM * 8);
    unsigned* pbhist = (unsigned*)take((size_t)NSIM * 16 * 4);
    float* dinv = (float*)take((size_t)2 * N * 4);
    int* offs = (int*)take((size_t)2 * (N + 1) * 4);
    int* cursor = (int*)take((size_t)2 * N * 4);
    int* esrc = (int*)take((size_t)2 * E * 4);
    unsigned short* xs = (unsigned short*)take((size_t)2 * N * 64 * 2);
    unsigned short* t1 = (unsigned short*)take((size_t)2 * N * 64 * 2);
    unsigned short* t3 = (unsigned short*)take((size_t)2 * N * 32 * 2);
    unsigned short* W1t = (unsigned short*)take(128 * 64 * 2);
    unsigned short* W2t = (unsigned short*)take(64 * 128 * 2);
    unsigned short* W3t = (unsigned short*)take(32 * 64 * 2);

    size_t zbytes = ((char*)cnt + (size_t)2 * N * 4) - (char*)gsum;
    int zn4 = (int)(zbytes / 16);

    // ---- CSR build + prep ----
    zero_prep<<<(zn4 + 255) / 256 + 3, 256, 0, stream>>>((float4*)gsum, zn4, W1, W2, W3,
                                                         W1t, W2t, W3t);
    count_tgt<<<dim3((E + 255) / 256, 2), 256, 0, stream>>>(ei1 + E, ei2 + E, cnt, N, E);
    scan_xscale<<<2 + (2 * N * 16 + 1023) / 1024, 1024, 0, stream>>>(
        cnt, offs, cursor, dinv, feat1, feat2, xs, N);
    scatter_src<<<dim3((E + 255) / 256, 2), 256, 0, stream>>>(ei1, ei2, ei1 + E, ei2 + E,
                                                              cursor, esrc, N, E);

    // ---- fused GCN pipeline ----
    fusedA<<<dim3(N / 16, 2), 256, 0, stream>>>(xs, W1t, b1, W2t, t1, offs, esrc, dinv,
                                                N, E);
    fusedB<<<dim3(N / 16, 2), 256, 0, stream>>>(t1, b2, W3t, t3, offs, esrc, dinv, N, E);
    agg3_pool<<<dim3(N / 32, 2), 256, 0, stream>>>(t3, offs, esrc, dinv, b3, af, afbf,
                                                   gsum, N, E);
    simA<<<NSIM + (N / 256) * 2, 256, 0, stream>>>(afbf, af, gsum, Wa, p12, pbmm, N, NSIM);
    simB<<<NSIM, 256, 0, stream>>>(afbf, afbf + (size_t)N * 32, N, NSIM, pbmm, pbhist);
    ntn_final<<<1, 256, 0, stream>>>(p12, Wt, V, bt, pbhist, NSIM, fc1W, fc1b, fc2W, fc2b,
                                     fc3W, fc3b, scW, scb, avg_v, (float*)d_out);
}

// Round 21
// 187.730 us; speedup vs baseline: 1.0030x; 1.0030x over previous
//
#include <hip/hip_runtime.h>
#include <math.h>

// ---------------------------------------------------------------------------
// SimGNN forward on MI355X (gfx950).  R19 = R17 +
//   fusedB gemm3 via MFMA (W3t bf16, same layout as fusedA's proven gemms)
//   SIM_CHUNK 2->4 with 8-bit pack flushed to 16-bit every 2 tiles
// ---------------------------------------------------------------------------

#define SIM_CHUNK 4
#define GS_PAD 16
#define GS_REP 8

using bf16x8 = __attribute__((ext_vector_type(8))) short;
using f32x4  = __attribute__((ext_vector_type(4))) float;

__device__ __forceinline__ unsigned short f2bf(float f) {  // RNE
    unsigned u = __float_as_uint(f);
    unsigned r = ((u >> 16) & 1u) + 0x7FFFu;
    return (unsigned short)((u + r) >> 16);
}
__device__ __forceinline__ void bf4_load(const unsigned short* __restrict__ p,
                                         float f[4]) {
    uint2 u = *(const uint2*)p;
    f[0] = __uint_as_float(u.x << 16);
    f[1] = __uint_as_float(u.x & 0xFFFF0000u);
    f[2] = __uint_as_float(u.y << 16);
    f[3] = __uint_as_float(u.y & 0xFFFF0000u);
}
__device__ __forceinline__ uint2 bf4_pack(float a, float b, float c, float d) {
    uint2 u;
    u.x = (unsigned)f2bf(a) | ((unsigned)f2bf(b) << 16);
    u.y = (unsigned)f2bf(c) | ((unsigned)f2bf(d) << 16);
    return u;
}

// ---- bf16 prescaled gather: returns h'[r] + sum_s h'[s] (f32 accum) ----
template <int F>
__device__ __forceinline__ float4 aggRowBF(const unsigned short* __restrict__ hp,
                                           const int* __restrict__ offs,
                                           const int* __restrict__ esrc,
                                           int r, int fq) {
    float f[4];
    bf4_load(&hp[(size_t)r * F + fq], f);
    float ax = f[0], ay = f[1], az = f[2], aw = f[3];
    int e = offs[r], e1 = offs[r + 1];
    for (; e + 4 <= e1; e += 4) {
        int s0 = esrc[e], s1 = esrc[e + 1], s2 = esrc[e + 2], s3 = esrc[e + 3];
        float f0[4], f1[4], f2[4], f3[4];
        bf4_load(&hp[(size_t)s0 * F + fq], f0);
        bf4_load(&hp[(size_t)s1 * F + fq], f1);
        bf4_load(&hp[(size_t)s2 * F + fq], f2);
        bf4_load(&hp[(size_t)s3 * F + fq], f3);
        ax += f0[0] + f1[0]; ay += f0[1] + f1[1];
        az += f0[2] + f1[2]; aw += f0[3] + f1[3];
        ax += f2[0] + f3[0]; ay += f2[1] + f3[1];
        az += f2[2] + f3[2]; aw += f2[3] + f3[3];
    }
    for (; e < e1; ++e) {
        int s = esrc[e];
        float fs[4];
        bf4_load(&hp[(size_t)s * F + fq], fs);
        ax += fs[0]; ay += fs[1]; az += fs[2]; aw += fs[3];
    }
    return make_float4(ax, ay, az, aw);
}

// ========= zero_prep: zero gsum|p12|cnt + transpose W1,W2,W3 to bf16 =======
__global__ void zero_prep(float4* __restrict__ p, int n4,
                          const float* __restrict__ W1, const float* __restrict__ W2,
                          const float* __restrict__ W3,
                          unsigned short* __restrict__ W1t,
                          unsigned short* __restrict__ W2t,
                          unsigned short* __restrict__ W3t) {
    int nzb = gridDim.x - 3;
    int b = blockIdx.x;
    if (b < nzb) {
        int i = b * 256 + threadIdx.x;
        if (i < n4) p[i] = make_float4(0.f, 0.f, 0.f, 0.f);
        return;
    }
    if (b == nzb) {        // W1t[c][k] = bf16(W1[k][c]), c<128, k<64
        for (int i = threadIdx.x; i < 128 * 64; i += 256) {
            int c = i >> 6, k = i & 63;
            W1t[c * 64 + k] = f2bf(W1[k * 128 + c]);
        }
    } else if (b == nzb + 1) {  // W2t[c][k] = bf16(W2[k][c]), c<64, k<128
        for (int i = threadIdx.x; i < 64 * 128; i += 256) {
            int c = i >> 7, k = i & 127;
            W2t[c * 128 + k] = f2bf(W2[k * 64 + c]);
        }
    } else {               // W3t[c][k] = bf16(W3[k][c]), c<32, k<64
        for (int i = threadIdx.x; i < 32 * 64; i += 256) {
            int c = i >> 6, k = i & 63;
            W3t[c * 64 + k] = f2bf(W3[k * 32 + c]);
        }
    }
}

__global__ void count_tgt(const int* __restrict__ t0, const int* __restrict__ t1,
                          int* __restrict__ cnt, int N, int E) {
    int g = blockIdx.y;
    const int* t = g ? t1 : t0;
    int i = blockIdx.x * 256 + threadIdx.x;
    if (i < E) atomicAdd(&cnt[g * N + t[i]], 1);
}

// ========= scan_xscale: blocks 0,1 = scan; rest = xscale ====================
__global__ __launch_bounds__(1024) void scan_xscale(const int* __restrict__ cnt_,
                                                    int* __restrict__ offs_,
                                                    int* __restrict__ cursor_,
                                                    float* __restrict__ dinv_,
                                                    const float* __restrict__ x1,
                                                    const float* __restrict__ x2,
                                                    unsigned short* __restrict__ xs,
                                                    int N) {
    int b = blockIdx.x;
    if (b < 2) {
        int g = b;
        const int* cnt = cnt_ + g * N;
        int* offs = offs_ + g * (N + 1);
        int* cursor = cursor_ + g * N;
        float* dinv = dinv_ + g * N;
        int tid = threadIdx.x, lane = tid & 63, wid = tid >> 6;
        int chunk = (N + 1023) >> 10;
        int base = tid * chunk;
        int s = 0;
        for (int i = 0; i < chunk; ++i) {
            int idx = base + i;
            if (idx < N) s += cnt[idx];
        }
        int v = s;
#pragma unroll
        for (int d = 1; d < 64; d <<= 1) {
            int u = __shfl_up(v, d);
            if (lane >= d) v += u;
        }
        __shared__ int wtot[16], wbase[16];
        if (lane == 63) wtot[wid] = v;
        __syncthreads();
        if (tid == 0) {
            int r = 0;
            for (int i = 0; i < 16; ++i) { wbase[i] = r; r += wtot[i]; }
            offs[N] = r;
        }
        __syncthreads();
        int run = wbase[wid] + (v - s);
        for (int i = 0; i < chunk; ++i) {
            int idx = base + i;
            if (idx < N) {
                int c = cnt[idx];
                offs[idx] = run;
                cursor[idx] = run;
                dinv[idx] = 1.0f / sqrtf((float)(c + 1));
                run += c;
            }
        }
        return;
    }
    int i = (b - 2) * 1024 + threadIdx.x;
    if (i >= 2 * N * 16) return;
    int row = i >> 4;
    int g = row >= N;
    const float* x = g ? x2 : x1;
    int r = row - (g ? N : 0);
    float4 v = ((const float4*)x)[(size_t)r * 16 + (i & 15)];
    float d = 1.0f / sqrtf((float)(cnt_[row] + 1));
    ((uint2*)xs)[i] = bf4_pack(d * v.x, d * v.y, d * v.z, d * v.w);
}

__global__ void scatter_src(const int* __restrict__ s0, const int* __restrict__ s1,
                            const int* __restrict__ t0, const int* __restrict__ t1,
                            int* __restrict__ cursor, int* __restrict__ esrc, int N, int E) {
    int g = blockIdx.y;
    const int* src = g ? s1 : s0;
    const int* tgt = g ? t1 : t0;
    int i = blockIdx.x * 256 + threadIdx.x;
    if (i < E) {
        int t = tgt[i];
        int pos = atomicAdd(&cursor[g * N + t], 1);
        esrc[g * E + pos] = src[i];
    }
}

// ========= fusedA: agg1(xs) -> MFMA gemm1(+b1,relu) -> MFMA gemm2 -> t1' ====
__global__ __launch_bounds__(256) void fusedA(const unsigned short* __restrict__ xs,
                                              const unsigned short* __restrict__ W1t,
                                              const float* __restrict__ b1,
                                              const unsigned short* __restrict__ W2t,
                                              unsigned short* __restrict__ t1,
                                              const int* __restrict__ offs_,
                                              const int* __restrict__ esrc_,
                                              const float* __restrict__ dinv_,
                                              int N, int E) {
    __shared__ unsigned short Xb[16][72];
    __shared__ unsigned short H1b[16][136];
    __shared__ float dtl[16];
    int g = blockIdx.y;
    const unsigned short* xp = xs + (size_t)(g ? N : 0) * 64;
    const int* offs = offs_ + g * (N + 1);
    const int* esrc = esrc_ + (size_t)g * E;
    const float* dinv = dinv_ + g * N;
    int rb = blockIdx.x * 16;
    int tid = threadIdx.x;
    int tc = tid & 15, tr = tid >> 4;
    if (tid < 16) dtl[tid] = dinv[rb + tid];
    {
        float dt_row = dinv[rb + tr];
        int fq = tc * 4;
        float4 v = aggRowBF<64>(xp, offs, esrc, rb + tr, fq);
        *(uint2*)&Xb[tr][fq] =
            bf4_pack(dt_row * v.x, dt_row * v.y, dt_row * v.z, dt_row * v.w);
    }
    __syncthreads();

    int lane = tid & 63, wv = tid >> 6;
    int lr = lane & 15;
    int kg = (lane >> 4) << 3;

    bf16x8 a0 = *(const bf16x8*)&Xb[lr][kg];
    bf16x8 a1 = *(const bf16x8*)&Xb[lr][32 + kg];

    f32x4 zero = {0.f, 0.f, 0.f, 0.f};
#pragma unroll
    for (int t = 0; t < 2; ++t) {
        int ct = wv + t * 4;
        const unsigned short* wb = W1t + (size_t)(ct * 16 + lr) * 64;
        bf16x8 b0 = *(const bf16x8*)&wb[kg];
        bf16x8 b1f = *(const bf16x8*)&wb[32 + kg];
        f32x4 acc = __builtin_amdgcn_mfma_f32_16x16x32_bf16(a0, b0, zero, 0, 0, 0);
        acc = __builtin_amdgcn_mfma_f32_16x16x32_bf16(a1, b1f, acc, 0, 0, 0);
        int col = ct * 16 + lr;
        float bias = b1[col];
#pragma unroll
        for (int r = 0; r < 4; ++r) {
            int row = (lane >> 4) * 4 + r;
            float v = fmaxf(acc[r] + bias, 0.f);
            H1b[row][col] = f2bf(v);
        }
    }
    __syncthreads();
    {
        int ct = wv;
        const unsigned short* wb = W2t + (size_t)(ct * 16 + lr) * 128;
        f32x4 acc = zero;
#pragma unroll
        for (int kb = 0; kb < 4; ++kb) {
            bf16x8 af = *(const bf16x8*)&H1b[lr][kb * 32 + kg];
            bf16x8 bf = *(const bf16x8*)&wb[kb * 32 + kg];
            acc = __builtin_amdgcn_mfma_f32_16x16x32_bf16(af, bf, acc, 0, 0, 0);
        }
        int col = ct * 16 + lr;
        size_t gbase = (size_t)(g ? N : 0) + rb;
#pragma unroll
        for (int r = 0; r < 4; ++r) {
            int row = (lane >> 4) * 4 + r;
            t1[(gbase + row) * 64 + col] = f2bf(dtl[row] * acc[r]);
        }
    }
}

// ========= fusedB: agg2(t1',+b2,relu) -> MFMA gemm3(W3t) -> t3' (bf16) ======
__global__ __launch_bounds__(256) void fusedB(const unsigned short* __restrict__ t1,
                                              const float* __restrict__ b2,
                                              const unsigned short* __restrict__ W3t,
                                              unsigned short* __restrict__ t3,
                                              const int* __restrict__ offs_,
                                              const int* __restrict__ esrc_,
                                              const float* __restrict__ dinv_,
                                              int N, int E) {
    __shared__ unsigned short Xb[16][72];
    __shared__ float dtl[16];
    int g = blockIdx.y;
    const unsigned short* hp = t1 + (size_t)(g ? N : 0) * 64;
    const int* offs = offs_ + g * (N + 1);
    const int* esrc = esrc_ + (size_t)g * E;
    const float* dinv = dinv_ + g * N;
    int rb = blockIdx.x * 16;
    int tid = threadIdx.x;
    int tc = tid & 15, tr = tid >> 4;
    if (tid < 16) dtl[tid] = dinv[rb + tid];
    {
        float dt_row = dinv[rb + tr];
        int fq = tc * 4;
        float4 bb = *(const float4*)&b2[fq];
        float4 v = aggRowBF<64>(hp, offs, esrc, rb + tr, fq);
        v.x = fmaxf(fmaf(dt_row, v.x, bb.x), 0.f);
        v.y = fmaxf(fmaf(dt_row, v.y, bb.y), 0.f);
        v.z = fmaxf(fmaf(dt_row, v.z, bb.z), 0.f);
        v.w = fmaxf(fmaf(dt_row, v.w, bb.w), 0.f);
        *(uint2*)&Xb[tr][fq] = bf4_pack(v.x, v.y, v.z, v.w);
    }
    __syncthreads();
    int lane = tid & 63, wv = tid >> 6;
    if (wv < 2) {  // gemm3: X(16x64) @ W3(64x32); wave wv -> col-tile wv
        int lr = lane & 15;
        int kg = (lane >> 4) << 3;
        bf16x8 a0 = *(const bf16x8*)&Xb[lr][kg];
        bf16x8 a1 = *(const bf16x8*)&Xb[lr][32 + kg];
        const unsigned short* wb = W3t + (size_t)(wv * 16 + lr) * 64;
        bf16x8 b0 = *(const bf16x8*)&wb[kg];
        bf16x8 b1f = *(const bf16x8*)&wb[32 + kg];
        f32x4 zero = {0.f, 0.f, 0.f, 0.f};
        f32x4 acc = __builtin_amdgcn_mfma_f32_16x16x32_bf16(a0, b0, zero, 0, 0, 0);
        acc = __builtin_amdgcn_mfma_f32_16x16x32_bf16(a1, b1f, acc, 0, 0, 0);
        int col = wv * 16 + lr;
        size_t gbase = (size_t)(g ? N : 0) + rb;
#pragma unroll
        for (int r = 0; r < 4; ++r) {
            int row = (lane >> 4) * 4 + r;
            t3[(gbase + row) * 32 + col] = f2bf(dtl[row] * acc[r]);
        }
    }
}

// ========= agg3 + pool (gsum) + bf16 mirror ================================
__global__ __launch_bounds__(256) void agg3_pool(const unsigned short* __restrict__ t3,
                                                 const int* __restrict__ offs_,
                                                 const int* __restrict__ esrc_,
                                                 const float* __restrict__ dinv_,
                                                 const float* __restrict__ b,
                                                 float* __restrict__ out,
                                                 unsigned short* __restrict__ outbf,
                                                 float* __restrict__ gsum, int N, int E) {
    int g = blockIdx.y;
    const unsigned short* hp = t3 + (size_t)(g ? N : 0) * 32;
    const int* offs = offs_ + g * (N + 1);
    const int* esrc = esrc_ + (size_t)g * E;
    const float* dinv = dinv_ + g * N;
    int fq = (threadIdx.x & 7) * 4;
    int t = blockIdx.x * 32 + threadIdx.x / 8;
    float dt_row = dinv[t];
    float4 v = aggRowBF<32>(hp, offs, esrc, t, fq);
    float4 bb = *(const float4*)&b[fq];
    v.x = fmaf(dt_row, v.x, bb.x); v.y = fmaf(dt_row, v.y, bb.y);
    v.z = fmaf(dt_row, v.z, bb.z); v.w = fmaf(dt_row, v.w, bb.w);
    *(float4*)&out[((size_t)(g * N + t)) * 32 + fq] = v;
    unsigned short r4[4] = {f2bf(v.x), f2bf(v.y), f2bf(v.z), f2bf(v.w)};
    *(uint2*)&outbf[((size_t)(g * N + t)) * 32 + fq] = *(uint2*)r4;
    __shared__ float ls[32];
    if (threadIdx.x < 32) ls[threadIdx.x] = 0.f;
    __syncthreads();
    atomicAdd(&ls[fq + 0], v.x);
    atomicAdd(&ls[fq + 1], v.y);
    atomicAdd(&ls[fq + 2], v.z);
    atomicAdd(&ls[fq + 3], v.w);
    __syncthreads();
    if (threadIdx.x < 32) {
        int rep = blockIdx.x & (GS_REP - 1);
        atomicAdd(&gsum[((g * GS_REP + rep) * 32 + threadIdx.x) * GS_PAD],
                  ls[threadIdx.x]);
    }
}

// ========= simA: sim min/max (blocks < NSIM) + attention pool (rest) ========
__global__ __launch_bounds__(256) void simA(const unsigned short* __restrict__ afbf,
                                            const float* __restrict__ af,
                                            const float* __restrict__ gsum,
                                            const float* __restrict__ Wa,
                                            float* __restrict__ p12,
                                            float2* __restrict__ pbmm, int N, int NSIM) {
    int bid = blockIdx.x;
    int tid = threadIdx.x;
    int lane = tid & 63, wv = tid >> 6;
    if (bid >= NSIM) {
        int pb = bid - NSIM;
        int npg = N / 256;
        int g = pb / npg;
        int r = (pb % npg) * 256 + tid;
        const float* afg = af + (size_t)g * N * 32;
        __shared__ float cm[32], ctxs[32];
        if (tid < 32) {
            float s = 0.f;
#pragma unroll
            for (int rep = 0; rep < GS_REP; ++rep)
                s += gsum[((g * GS_REP + rep) * 32 + tid) * GS_PAD];
            cm[tid] = s / (float)N;
        }
        __syncthreads();
        if (tid < 32) {
            float s = 0.f;
            for (int d = 0; d < 32; ++d) s = fmaf(cm[d], Wa[d * 32 + tid], s);
            ctxs[tid] = tanhf(s);
        }
        __syncthreads();
        float rowv[32];
        const float4* row = (const float4*)(afg + (size_t)r * 32);
        float dot = 0.f;
#pragma unroll
        for (int q = 0; q < 8; ++q) {
            float4 v = row[q];
            rowv[q * 4 + 0] = v.x; rowv[q * 4 + 1] = v.y;
            rowv[q * 4 + 2] = v.z; rowv[q * 4 + 3] = v.w;
            dot = fmaf(v.x, ctxs[q * 4 + 0], dot);
            dot = fmaf(v.y, ctxs[q * 4 + 1], dot);
            dot = fmaf(v.z, ctxs[q * 4 + 2], dot);
            dot = fmaf(v.w, ctxs[q * 4 + 3], dot);
        }
        float att = 1.f / (1.f + expf(-dot));
        __shared__ float wsum[4][32];
#pragma unroll
        for (int f = 0; f < 32; ++f) {
            float v = att * rowv[f];
#pragma unroll
            for (int off = 1; off < 64; off <<= 1) v += __shfl_xor(v, off);
            if (lane == 0) wsum[wv][f] = v;
        }
        __syncthreads();
        if (tid < 32) {
            float s = wsum[0][tid] + wsum[1][tid] + wsum[2][tid] + wsum[3][tid];
            atomicAdd(&p12[g * 32 + tid], s);
        }
        return;
    }
    const unsigned short* a1 = afbf;
    const unsigned short* a2 = afbf + (size_t)N * 32;
    int nb = N >> 7;
    int nchunk = nb / SIM_CHUNK;
    int by = bid / nchunk;
    int ch = bid % nchunk;
    int r16 = lane & 15, kg = (lane >> 4) << 3;
    const unsigned short* arow = a1 + ((size_t)(by * 128 + (wv >> 1) * 64 + r16)) * 32 + kg;
    bf16x8 afr[4];
#pragma unroll
    for (int m = 0; m < 4; ++m) afr[m] = *(const bf16x8*)(arow + m * 16 * 32);
    float mn = 1e30f, mx = -1e30f;
#pragma unroll
    for (int t = 0; t < SIM_CHUNK; ++t) {
        int bx = ch * SIM_CHUNK + t;
        const unsigned short* brow =
            a2 + ((size_t)(bx * 128 + (wv & 1) * 64 + r16)) * 32 + kg;
        bf16x8 bfr[4];
#pragma unroll
        for (int n = 0; n < 4; ++n) bfr[n] = *(const bf16x8*)(brow + n * 16 * 32);
        f32x4 zero = {0.f, 0.f, 0.f, 0.f};
        f32x4 acc[4][4];
#pragma unroll
        for (int m = 0; m < 4; ++m)
#pragma unroll
            for (int n = 0; n < 4; ++n)
                acc[m][n] =
                    __builtin_amdgcn_mfma_f32_16x16x32_bf16(afr[m], bfr[n], zero, 0, 0, 0);
#pragma unroll
        for (int m = 0; m < 4; ++m)
#pragma unroll
            for (int n = 0; n < 4; ++n)
#pragma unroll
                for (int e = 0; e < 4; ++e) {
                    float v = acc[m][n][e];
                    mn = fminf(mn, v);
                    mx = fmaxf(mx, v);
                }
    }
#pragma unroll
    for (int off = 1; off < 64; off <<= 1) {
        mn = fminf(mn, __shfl_xor(mn, off));
        mx = fmaxf(mx, __shfl_xor(mx, off));
    }
    __shared__ float wmn[4], wmx[4];
    if (lane == 0) { wmn[wv] = mn; wmx[wv] = mx; }
    __syncthreads();
    if (tid == 0) {
        float bmn = fminf(fminf(wmn[0], wmn[1]), fminf(wmn[2], wmn[3]));
        float bmx = fmaxf(fmaxf(wmx[0], wmx[1]), fmaxf(wmx[2], wmx[3]));
        pbmm[bid] = make_float2(bmn, bmx);
    }
}

// ========= simB: histogram (pack 8-bit, flush to 16-bit every 2 tiles) ======
__global__ __launch_bounds__(256) void simB(const unsigned short* __restrict__ a1,
                                            const unsigned short* __restrict__ a2,
                                            int N, int nblk,
                                            const float2* __restrict__ pbmm,
                                            unsigned* __restrict__ pbhist) {
    int nb = N >> 7;
    int nchunk = nb / SIM_CHUNK;
    int by = blockIdx.x / nchunk;
    int ch = blockIdx.x % nchunk;
    int w = threadIdx.x >> 6, lane = threadIdx.x & 63;
    int r16 = lane & 15, kg = (lane >> 4) << 3;
    __shared__ unsigned hs[16];
    __shared__ float mnmx[2];
    if (threadIdx.x < 16) hs[threadIdx.x] = 0;
    {
        float mn2 = 1e30f, mx2 = -1e30f;
        for (int i = threadIdx.x; i < nblk; i += 256) {
            float2 vv = pbmm[i];
            mn2 = fminf(mn2, vv.x);
            mx2 = fmaxf(mx2, vv.y);
        }
#pragma unroll
        for (int off = 1; off < 64; off <<= 1) {
            mn2 = fminf(mn2, __shfl_xor(mn2, off));
            mx2 = fmaxf(mx2, __shfl_xor(mx2, off));
        }
        __shared__ float wmn2[4], wmx2[4];
        if (lane == 0) { wmn2[w] = mn2; wmx2[w] = mx2; }
        __syncthreads();
        if (threadIdx.x == 0) {
            mnmx[0] = fminf(fminf(wmn2[0], wmn2[1]), fminf(wmn2[2], wmn2[3]));
            mnmx[1] = fmaxf(fmaxf(wmx2[0], wmx2[1]), fmaxf(wmx2[2], wmx2[3]));
        }
        __syncthreads();
    }
    float mnv = mnmx[0], mxv = mnmx[1];
    float width = (mxv > mnv) ? (mxv - mnv) : 1.0f;
    float scale = 16.0f / width;
    float nbias = -mnv * scale;
    const unsigned short* arow = a1 + ((size_t)(by * 128 + (w >> 1) * 64 + r16)) * 32 + kg;
    bf16x8 afr[4];
#pragma unroll
    for (int m = 0; m < 4; ++m) afr[m] = *(const bf16x8*)(arow + m * 16 * 32);
    unsigned hh[8] = {0u, 0u, 0u, 0u, 0u, 0u, 0u, 0u};
#pragma unroll
    for (int half = 0; half < SIM_CHUNK / 2; ++half) {
        unsigned h4_0 = 0, h4_1 = 0, h4_2 = 0, h4_3 = 0;
#pragma unroll
        for (int t = 0; t < 2; ++t) {
            int bx = ch * SIM_CHUNK + half * 2 + t;
            const unsigned short* brow =
                a2 + ((size_t)(bx * 128 + (w & 1) * 64 + r16)) * 32 + kg;
            bf16x8 bfr[4];
#pragma unroll
            for (int n = 0; n < 4; ++n) bfr[n] = *(const bf16x8*)(brow + n * 16 * 32);
            f32x4 zero = {0.f, 0.f, 0.f, 0.f};
            f32x4 acc[4][4];
#pragma unroll
            for (int m = 0; m < 4; ++m)
#pragma unroll
                for (int n = 0; n < 4; ++n)
                    acc[m][n] = __builtin_amdgcn_mfma_f32_16x16x32_bf16(afr[m], bfr[n],
                                                                        zero, 0, 0, 0);
#pragma unroll
            for (int m = 0; m < 4; ++m)
#pragma unroll
                for (int n = 0; n < 4; ++n)
#pragma unroll
                    for (int e = 0; e < 4; ++e) {
                        float v = acc[m][n][e];
                        int bin = (int)fmaf(v, scale, nbias);
                        bin = bin < 0 ? 0 : (bin > 15 ? 15 : bin);
                        unsigned wbit = 1u << ((bin & 3) << 3);
                        int hi = bin >> 2;
                        h4_0 += (hi == 0) ? wbit : 0u;
                        h4_1 += (hi == 1) ? wbit : 0u;
                        h4_2 += (hi == 2) ? wbit : 0u;
                        h4_3 += (hi == 3) ? wbit : 0u;
                    }
        }
        // flush 8-bit packs (max 128/bin) into 16-bit accumulators
        hh[0] += h4_0 & 0x00FF00FFu; hh[1] += (h4_0 >> 8) & 0x00FF00FFu;
        hh[2] += h4_1 & 0x00FF00FFu; hh[3] += (h4_1 >> 8) & 0x00FF00FFu;
        hh[4] += h4_2 & 0x00FF00FFu; hh[5] += (h4_2 >> 8) & 0x00FF00FFu;
        hh[6] += h4_3 & 0x00FF00FFu; hh[7] += (h4_3 >> 8) & 0x00FF00FFu;
    }
#pragma unroll
    for (int off = 1; off < 64; off <<= 1) {
#pragma unroll
        for (int q = 0; q < 8; ++q) hh[q] += (unsigned)__shfl_xor((int)hh[q], off);
    }
    __syncthreads();
    if (lane < 16) {
        int q = lane >> 2, r = lane & 3;
        unsigned word = hh[2 * q + (r & 1)];
        unsigned val = (r < 2) ? (word & 0xFFFFu) : (word >> 16);
        atomicAdd(&hs[lane], val);
    }
    __syncthreads();
    if (threadIdx.x < 16)
        pbhist[(size_t)blockIdx.x * 16 + threadIdx.x] = hs[threadIdx.x];
}

// ========= hist reduce + NTN + MLP head ====================================
__global__ __launch_bounds__(256) void ntn_final(
    const float* __restrict__ p12, const float* __restrict__ Wt,
    const float* __restrict__ V, const float* __restrict__ bt,
    const unsigned* __restrict__ pbhist, int nblk,
    const float* __restrict__ fc1W, const float* __restrict__ fc1b,
    const float* __restrict__ fc2W, const float* __restrict__ fc2b,
    const float* __restrict__ fc3W, const float* __restrict__ fc3b,
    const float* __restrict__ scW, const float* __restrict__ scb,
    const float* __restrict__ avg_v, float* __restrict__ out) {
    __shared__ float p1l[32], p2l[32];
    __shared__ float scp[16][17];
    __shared__ unsigned hs[16];
    __shared__ float sc[16];
    __shared__ float sfeat[32];
    __shared__ float h1s[16];
    int t = threadIdx.x;
    if (t < 16) hs[t] = 0;
    if (t < 32) p1l[t] = p12[t];
    else if (t < 64) p2l[t - 32] = p12[t];
    __syncthreads();
    {
        const uint4* pb = (const uint4*)pbhist;
        int total = nblk * 4;
        uint4 a = {0u, 0u, 0u, 0u};
        for (int i = t; i < total; i += 256) {
            uint4 v = pb[i];
            a.x += v.x; a.y += v.y; a.z += v.z; a.w += v.w;
        }
#pragma unroll
        for (int off = 4; off < 64; off <<= 1) {
            a.x += (unsigned)__shfl_xor((int)a.x, off);
            a.y += (unsigned)__shfl_xor((int)a.y, off);
            a.z += (unsigned)__shfl_xor((int)a.z, off);
            a.w += (unsigned)__shfl_xor((int)a.w, off);
        }
        int lane = t & 63;
        if (lane < 4) {
            atomicAdd(&hs[lane * 4 + 0], a.x);
            atomicAdd(&hs[lane * 4 + 1], a.y);
            atomicAdd(&hs[lane * 4 + 2], a.z);
            atomicAdd(&hs[lane * 4 + 3], a.w);
        }
    }
    {
        int k = t & 15, dp = t >> 4;
        float s = 0.f;
#pragma unroll
        for (int dd = 0; dd < 2; ++dd) {
            int d = dp * 2 + dd;
            float a = p1l[d];
            for (int e = 0; e < 32; ++e)
                s = fmaf(a * p2l[e], Wt[(d * 32 + e) * 16 + k], s);
        }
        scp[dp][k] = s;
    }
    __syncthreads();
    if (t < 16) {
        float s = 0.f;
#pragma unroll
        for (int dp = 0; dp < 16; ++dp) s += scp[dp][t];
        float bl = 0.f;
        for (int m = 0; m < 32; ++m) bl = fmaf(V[t * 64 + m], p1l[m], bl);
        for (int m = 0; m < 32; ++m) bl = fmaf(V[t * 64 + 32 + m], p2l[m], bl);
        sc[t] = fmaxf(s + bl + bt[t], 0.f);
    }
    __syncthreads();
    if (t < 16) sfeat[t] = sc[t];
    if (t == 16) {
        unsigned tot = 0;
        for (int b = 0; b < 16; ++b) tot += hs[b];
        float ftot = (float)tot;
        for (int b = 0; b < 16; ++b) sfeat[16 + b] = (float)hs[b] / ftot;
    }
    __syncthreads();
    if (t < 16) {
        float a = fc1b[t];
        for (int m = 0; m < 32; ++m) a = fmaf(sfeat[m], fc1W[m * 16 + t], a);
        h1s[t] = fmaxf(a, 0.f);
    }
    __syncthreads();
    if (t != 0) return;
    float h2[8];
    for (int r = 0; r < 8; ++r) {
        float a = fc2b[r];
        for (int m = 0; m < 16; ++m) a = fmaf(h1s[m], fc2W[m * 8 + r], a);
        h2[r] = fmaxf(a, 0.f);
    }
    float h3[4];
    for (int r = 0; r < 4; ++r) {
        float a = fc3b[r];
        for (int m = 0; m < 8; ++m) a = fmaf(h2[m], fc3W[m * 4 + r], a);
        h3[r] = fmaxf(a, 0.f);
    }
    float z = scb[0];
    for (int m = 0; m < 4; ++m) z = fmaf(h3[m], scW[m], z);
    float sig = 1.f / (1.f + expf(-z));
    out[0] = sig;
    out[1] = -logf(sig) * avg_v[0];
}

// ---------------------------------------------------------------------------
extern "C" void kernel_launch(void* const* d_in, const int* in_sizes, int n_in,
                              void* d_out, int out_size, void* d_ws, size_t ws_size,
                              hipStream_t stream) {
    (void)n_in; (void)out_size; (void)ws_size;
    const int* ei1 = (const int*)d_in[0];
    const int* ei2 = (const int*)d_in[1];
    const float* feat1 = (const float*)d_in[2];
    const float* feat2 = (const float*)d_in[3];
    const float* avg_v = (const float*)d_in[4];
    const float* W1 = (const float*)d_in[5];
    const float* b1 = (const float*)d_in[6];
    const float* W2 = (const float*)d_in[7];
    const float* b2 = (const float*)d_in[8];
    const float* W3 = (const float*)d_in[9];
    const float* b3 = (const float*)d_in[10];
    const float* Wa = (const float*)d_in[11];
    const float* Wt = (const float*)d_in[12];
    const float* V = (const float*)d_in[13];
    const float* bt = (const float*)d_in[14];
    const float* fc1W = (const float*)d_in[15];
    const float* fc1b = (const float*)d_in[16];
    const float* fc2W = (const float*)d_in[17];
    const float* fc2b = (const float*)d_in[18];
    const float* fc3W = (const float*)d_in[19];
    const float* fc3b = (const float*)d_in[20];
    const float* scW = (const float*)d_in[21];
    const float* scb = (const float*)d_in[22];

    const int E = in_sizes[0] / 2;
    const int N = in_sizes[2] / 64;
    const int nb = N / 128;
    const int nchunk = nb / SIM_CHUNK;
    const int NSIM = nb * nchunk;

    // ---- workspace layout ----
    char* w = (char*)d_ws;
    size_t off = 0;
    auto take = [&](size_t bytes) -> char* {
        char* p = w + off;
        off = (off + bytes + 255) & ~(size_t)255;
        return p;
    };
    float* gsum = (float*)take((size_t)2 * GS_REP * 32 * GS_PAD * 4);  // zero start
    float* p12 = (float*)take(64 * 4);
    int* cnt = (int*)take((size_t)2 * N * 4);                          // zero end
    float* af = (float*)take((size_t)2 * N * 32 * 4);
    unsigned short* afbf = (unsigned short*)take((size_t)2 * N * 32 * 2);
    float2* pbmm = (float2*)take((size_t)NSIM * 8);
    unsigned* pbhist = (unsigned*)take((size_t)NSIM * 16 * 4);
    float* dinv = (float*)take((size_t)2 * N * 4);
    int* offs = (int*)take((size_t)2 * (N + 1) * 4);
    int* cursor = (int*)take((size_t)2 * N * 4);
    int* esrc = (int*)take((size_t)2 * E * 4);
    unsigned short* xs = (unsigned short*)take((size_t)2 * N * 64 * 2);
    unsigned short* t1 = (unsigned short*)take((size_t)2 * N * 64 * 2);
    unsigned short* t3 = (unsigned short*)take((size_t)2 * N * 32 * 2);
    unsigned short* W1t = (unsigned short*)take(128 * 64 * 2);
    unsigned short* W2t = (unsigned short*)take(64 * 128 * 2);
    unsigned short* W3t = (unsigned short*)take(32 * 64 * 2);

    size_t zbytes = ((char*)cnt + (size_t)2 * N * 4) - (char*)gsum;
    int zn4 = (int)(zbytes / 16);

    // ---- CSR build + prep ----
    zero_prep<<<(zn4 + 255) / 256 + 3, 256, 0, stream>>>((float4*)gsum, zn4, W1, W2, W3,
                                                         W1t, W2t, W3t);
    count_tgt<<<dim3((E + 255) / 256, 2), 256, 0, stream>>>(ei1 + E, ei2 + E, cnt, N, E);
    scan_xscale<<<2 + (2 * N * 16 + 1023) / 1024, 1024, 0, stream>>>(
        cnt, offs, cursor, dinv, feat1, feat2, xs, N);
    scatter_src<<<dim3((E + 255) / 256, 2), 256, 0, stream>>>(ei1, ei2, ei1 + E, ei2 + E,
                                                              cursor, esrc, N, E);

    // ---- fused GCN pipeline ----
    fusedA<<<dim3(N / 16, 2), 256, 0, stream>>>(xs, W1t, b1, W2t, t1, offs, esrc, dinv,
                                                N, E);
    fusedB<<<dim3(N / 16, 2), 256, 0, stream>>>(t1, b2, W3t, t3, offs, esrc, dinv, N, E);
    agg3_pool<<<dim3(N / 32, 2), 256, 0, stream>>>(t3, offs, esrc, dinv, b3, af, afbf,
                                                   gsum, N, E);
    simA<<<NSIM + (N / 256) * 2, 256, 0, stream>>>(afbf, af, gsum, Wa, p12, pbmm, N, NSIM);
    simB<<<NSIM, 256, 0, stream>>>(afbf, afbf + (size_t)N * 32, N, NSIM, pbmm, pbhist);
    ntn_final<<<1, 256, 0, stream>>>(p12, Wt, V, bt, pbhist, NSIM, fc1W, fc1b, fc2W, fc2b,
                                     fc3W, fc3b, scW, scb, avg_v, (float*)d_out);
}

// Round 22
// 185.524 us; speedup vs baseline: 1.0149x; 1.0119x over previous
//
#include <hip/hip_runtime.h>
#include <math.h>

// ---------------------------------------------------------------------------
// SimGNN forward on MI355X (gfx950).  R20 = R19 +
//   int4-vectorized count_tgt / scatter_src (4 edges per thread)
//   SIM_CHUNK 4->8 (flush-to-16bit cadence unchanged: every 2 tiles)
// ---------------------------------------------------------------------------

#define SIM_CHUNK 8
#define GS_PAD 16
#define GS_REP 8

using bf16x8 = __attribute__((ext_vector_type(8))) short;
using f32x4  = __attribute__((ext_vector_type(4))) float;

__device__ __forceinline__ unsigned short f2bf(float f) {  // RNE
    unsigned u = __float_as_uint(f);
    unsigned r = ((u >> 16) & 1u) + 0x7FFFu;
    return (unsigned short)((u + r) >> 16);
}
__device__ __forceinline__ void bf4_load(const unsigned short* __restrict__ p,
                                         float f[4]) {
    uint2 u = *(const uint2*)p;
    f[0] = __uint_as_float(u.x << 16);
    f[1] = __uint_as_float(u.x & 0xFFFF0000u);
    f[2] = __uint_as_float(u.y << 16);
    f[3] = __uint_as_float(u.y & 0xFFFF0000u);
}
__device__ __forceinline__ uint2 bf4_pack(float a, float b, float c, float d) {
    uint2 u;
    u.x = (unsigned)f2bf(a) | ((unsigned)f2bf(b) << 16);
    u.y = (unsigned)f2bf(c) | ((unsigned)f2bf(d) << 16);
    return u;
}

// ---- bf16 prescaled gather: returns h'[r] + sum_s h'[s] (f32 accum) ----
template <int F>
__device__ __forceinline__ float4 aggRowBF(const unsigned short* __restrict__ hp,
                                           const int* __restrict__ offs,
                                           const int* __restrict__ esrc,
                                           int r, int fq) {
    float f[4];
    bf4_load(&hp[(size_t)r * F + fq], f);
    float ax = f[0], ay = f[1], az = f[2], aw = f[3];
    int e = offs[r], e1 = offs[r + 1];
    for (; e + 4 <= e1; e += 4) {
        int s0 = esrc[e], s1 = esrc[e + 1], s2 = esrc[e + 2], s3 = esrc[e + 3];
        float f0[4], f1[4], f2[4], f3[4];
        bf4_load(&hp[(size_t)s0 * F + fq], f0);
        bf4_load(&hp[(size_t)s1 * F + fq], f1);
        bf4_load(&hp[(size_t)s2 * F + fq], f2);
        bf4_load(&hp[(size_t)s3 * F + fq], f3);
        ax += f0[0] + f1[0]; ay += f0[1] + f1[1];
        az += f0[2] + f1[2]; aw += f0[3] + f1[3];
        ax += f2[0] + f3[0]; ay += f2[1] + f3[1];
        az += f2[2] + f3[2]; aw += f2[3] + f3[3];
    }
    for (; e < e1; ++e) {
        int s = esrc[e];
        float fs[4];
        bf4_load(&hp[(size_t)s * F + fq], fs);
        ax += fs[0]; ay += fs[1]; az += fs[2]; aw += fs[3];
    }
    return make_float4(ax, ay, az, aw);
}

// ========= zero_prep: zero gsum|p12|cnt + transpose W1,W2,W3 to bf16 =======
__global__ void zero_prep(float4* __restrict__ p, int n4,
                          const float* __restrict__ W1, const float* __restrict__ W2,
                          const float* __restrict__ W3,
                          unsigned short* __restrict__ W1t,
                          unsigned short* __restrict__ W2t,
                          unsigned short* __restrict__ W3t) {
    int nzb = gridDim.x - 3;
    int b = blockIdx.x;
    if (b < nzb) {
        int i = b * 256 + threadIdx.x;
        if (i < n4) p[i] = make_float4(0.f, 0.f, 0.f, 0.f);
        return;
    }
    if (b == nzb) {
        for (int i = threadIdx.x; i < 128 * 64; i += 256) {
            int c = i >> 6, k = i & 63;
            W1t[c * 64 + k] = f2bf(W1[k * 128 + c]);
        }
    } else if (b == nzb + 1) {
        for (int i = threadIdx.x; i < 64 * 128; i += 256) {
            int c = i >> 7, k = i & 127;
            W2t[c * 128 + k] = f2bf(W2[k * 64 + c]);
        }
    } else {
        for (int i = threadIdx.x; i < 32 * 64; i += 256) {
            int c = i >> 6, k = i & 63;
            W3t[c * 64 + k] = f2bf(W3[k * 32 + c]);
        }
    }
}

// ========= count_tgt: int4 (4 edges per thread) =============================
__global__ void count_tgt(const int* __restrict__ t0, const int* __restrict__ t1,
                          int* __restrict__ cnt, int N, int E4) {
    int g = blockIdx.y;
    const int4* t = (const int4*)(g ? t1 : t0);
    int i = blockIdx.x * 256 + threadIdx.x;
    if (i < E4) {
        int4 v = t[i];
        int* c = cnt + g * N;
        atomicAdd(&c[v.x], 1);
        atomicAdd(&c[v.y], 1);
        atomicAdd(&c[v.z], 1);
        atomicAdd(&c[v.w], 1);
    }
}

// ========= scan_xscale: blocks 0,1 = scan; rest = xscale ====================
__global__ __launch_bounds__(1024) void scan_xscale(const int* __restrict__ cnt_,
                                                    int* __restrict__ offs_,
                                                    int* __restrict__ cursor_,
                                                    float* __restrict__ dinv_,
                                                    const float* __restrict__ x1,
                                                    const float* __restrict__ x2,
                                                    unsigned short* __restrict__ xs,
                                                    int N) {
    int b = blockIdx.x;
    if (b < 2) {
        int g = b;
        const int* cnt = cnt_ + g * N;
        int* offs = offs_ + g * (N + 1);
        int* cursor = cursor_ + g * N;
        float* dinv = dinv_ + g * N;
        int tid = threadIdx.x, lane = tid & 63, wid = tid >> 6;
        int chunk = (N + 1023) >> 10;
        int base = tid * chunk;
        int s = 0;
        for (int i = 0; i < chunk; ++i) {
            int idx = base + i;
            if (idx < N) s += cnt[idx];
        }
        int v = s;
#pragma unroll
        for (int d = 1; d < 64; d <<= 1) {
            int u = __shfl_up(v, d);
            if (lane >= d) v += u;
        }
        __shared__ int wtot[16], wbase[16];
        if (lane == 63) wtot[wid] = v;
        __syncthreads();
        if (tid == 0) {
            int r = 0;
            for (int i = 0; i < 16; ++i) { wbase[i] = r; r += wtot[i]; }
            offs[N] = r;
        }
        __syncthreads();
        int run = wbase[wid] + (v - s);
        for (int i = 0; i < chunk; ++i) {
            int idx = base + i;
            if (idx < N) {
                int c = cnt[idx];
                offs[idx] = run;
                cursor[idx] = run;
                dinv[idx] = 1.0f / sqrtf((float)(c + 1));
                run += c;
            }
        }
        return;
    }
    int i = (b - 2) * 1024 + threadIdx.x;
    if (i >= 2 * N * 16) return;
    int row = i >> 4;
    int g = row >= N;
    const float* x = g ? x2 : x1;
    int r = row - (g ? N : 0);
    float4 v = ((const float4*)x)[(size_t)r * 16 + (i & 15)];
    float d = 1.0f / sqrtf((float)(cnt_[row] + 1));
    ((uint2*)xs)[i] = bf4_pack(d * v.x, d * v.y, d * v.z, d * v.w);
}

// ========= scatter_src: int4 (4 edges per thread) ===========================
__global__ void scatter_src(const int* __restrict__ s0, const int* __restrict__ s1,
                            const int* __restrict__ t0, const int* __restrict__ t1,
                            int* __restrict__ cursor, int* __restrict__ esrc,
                            int N, int E, int E4) {
    int g = blockIdx.y;
    const int4* src = (const int4*)(g ? s1 : s0);
    const int4* tgt = (const int4*)(g ? t1 : t0);
    int i = blockIdx.x * 256 + threadIdx.x;
    if (i < E4) {
        int4 sv = src[i];
        int4 tv = tgt[i];
        int* cur = cursor + g * N;
        int* es = esrc + (size_t)g * E;
        int p0 = atomicAdd(&cur[tv.x], 1); es[p0] = sv.x;
        int p1 = atomicAdd(&cur[tv.y], 1); es[p1] = sv.y;
        int p2 = atomicAdd(&cur[tv.z], 1); es[p2] = sv.z;
        int p3 = atomicAdd(&cur[tv.w], 1); es[p3] = sv.w;
    }
}

// ========= fusedA: agg1(xs) -> MFMA gemm1(+b1,relu) -> MFMA gemm2 -> t1' ====
__global__ __launch_bounds__(256) void fusedA(const unsigned short* __restrict__ xs,
                                              const unsigned short* __restrict__ W1t,
                                              const float* __restrict__ b1,
                                              const unsigned short* __restrict__ W2t,
                                              unsigned short* __restrict__ t1,
                                              const int* __restrict__ offs_,
                                              const int* __restrict__ esrc_,
                                              const float* __restrict__ dinv_,
                                              int N, int E) {
    __shared__ unsigned short Xb[16][72];
    __shared__ unsigned short H1b[16][136];
    __shared__ float dtl[16];
    int g = blockIdx.y;
    const unsigned short* xp = xs + (size_t)(g ? N : 0) * 64;
    const int* offs = offs_ + g * (N + 1);
    const int* esrc = esrc_ + (size_t)g * E;
    const float* dinv = dinv_ + g * N;
    int rb = blockIdx.x * 16;
    int tid = threadIdx.x;
    int tc = tid & 15, tr = tid >> 4;
    if (tid < 16) dtl[tid] = dinv[rb + tid];
    {
        float dt_row = dinv[rb + tr];
        int fq = tc * 4;
        float4 v = aggRowBF<64>(xp, offs, esrc, rb + tr, fq);
        *(uint2*)&Xb[tr][fq] =
            bf4_pack(dt_row * v.x, dt_row * v.y, dt_row * v.z, dt_row * v.w);
    }
    __syncthreads();

    int lane = tid & 63, wv = tid >> 6;
    int lr = lane & 15;
    int kg = (lane >> 4) << 3;

    bf16x8 a0 = *(const bf16x8*)&Xb[lr][kg];
    bf16x8 a1 = *(const bf16x8*)&Xb[lr][32 + kg];

    f32x4 zero = {0.f, 0.f, 0.f, 0.f};
#pragma unroll
    for (int t = 0; t < 2; ++t) {
        int ct = wv + t * 4;
        const unsigned short* wb = W1t + (size_t)(ct * 16 + lr) * 64;
        bf16x8 b0 = *(const bf16x8*)&wb[kg];
        bf16x8 b1f = *(const bf16x8*)&wb[32 + kg];
        f32x4 acc = __builtin_amdgcn_mfma_f32_16x16x32_bf16(a0, b0, zero, 0, 0, 0);
        acc = __builtin_amdgcn_mfma_f32_16x16x32_bf16(a1, b1f, acc, 0, 0, 0);
        int col = ct * 16 + lr;
        float bias = b1[col];
#pragma unroll
        for (int r = 0; r < 4; ++r) {
            int row = (lane >> 4) * 4 + r;
            float v = fmaxf(acc[r] + bias, 0.f);
            H1b[row][col] = f2bf(v);
        }
    }
    __syncthreads();
    {
        int ct = wv;
        const unsigned short* wb = W2t + (size_t)(ct * 16 + lr) * 128;
        f32x4 acc = zero;
#pragma unroll
        for (int kb = 0; kb < 4; ++kb) {
            bf16x8 af = *(const bf16x8*)&H1b[lr][kb * 32 + kg];
            bf16x8 bf = *(const bf16x8*)&wb[kb * 32 + kg];
            acc = __builtin_amdgcn_mfma_f32_16x16x32_bf16(af, bf, acc, 0, 0, 0);
        }
        int col = ct * 16 + lr;
        size_t gbase = (size_t)(g ? N : 0) + rb;
#pragma unroll
        for (int r = 0; r < 4; ++r) {
            int row = (lane >> 4) * 4 + r;
            t1[(gbase + row) * 64 + col] = f2bf(dtl[row] * acc[r]);
        }
    }
}

// ========= fusedB: agg2(t1',+b2,relu) -> MFMA gemm3(W3t) -> t3' (bf16) ======
__global__ __launch_bounds__(256) void fusedB(const unsigned short* __restrict__ t1,
                                              const float* __restrict__ b2,
                                              const unsigned short* __restrict__ W3t,
                                              unsigned short* __restrict__ t3,
                                              const int* __restrict__ offs_,
                                              const int* __restrict__ esrc_,
                                              const float* __restrict__ dinv_,
                                              int N, int E) {
    __shared__ unsigned short Xb[16][72];
    __shared__ float dtl[16];
    int g = blockIdx.y;
    const unsigned short* hp = t1 + (size_t)(g ? N : 0) * 64;
    const int* offs = offs_ + g * (N + 1);
    const int* esrc = esrc_ + (size_t)g * E;
    const float* dinv = dinv_ + g * N;
    int rb = blockIdx.x * 16;
    int tid = threadIdx.x;
    int tc = tid & 15, tr = tid >> 4;
    if (tid < 16) dtl[tid] = dinv[rb + tid];
    {
        float dt_row = dinv[rb + tr];
        int fq = tc * 4;
        float4 bb = *(const float4*)&b2[fq];
        float4 v = aggRowBF<64>(hp, offs, esrc, rb + tr, fq);
        v.x = fmaxf(fmaf(dt_row, v.x, bb.x), 0.f);
        v.y = fmaxf(fmaf(dt_row, v.y, bb.y), 0.f);
        v.z = fmaxf(fmaf(dt_row, v.z, bb.z), 0.f);
        v.w = fmaxf(fmaf(dt_row, v.w, bb.w), 0.f);
        *(uint2*)&Xb[tr][fq] = bf4_pack(v.x, v.y, v.z, v.w);
    }
    __syncthreads();
    int lane = tid & 63, wv = tid >> 6;
    if (wv < 2) {
        int lr = lane & 15;
        int kg = (lane >> 4) << 3;
        bf16x8 a0 = *(const bf16x8*)&Xb[lr][kg];
        bf16x8 a1 = *(const bf16x8*)&Xb[lr][32 + kg];
        const unsigned short* wb = W3t + (size_t)(wv * 16 + lr) * 64;
        bf16x8 b0 = *(const bf16x8*)&wb[kg];
        bf16x8 b1f = *(const bf16x8*)&wb[32 + kg];
        f32x4 zero = {0.f, 0.f, 0.f, 0.f};
        f32x4 acc = __builtin_amdgcn_mfma_f32_16x16x32_bf16(a0, b0, zero, 0, 0, 0);
        acc = __builtin_amdgcn_mfma_f32_16x16x32_bf16(a1, b1f, acc, 0, 0, 0);
        int col = wv * 16 + lr;
        size_t gbase = (size_t)(g ? N : 0) + rb;
#pragma unroll
        for (int r = 0; r < 4; ++r) {
            int row = (lane >> 4) * 4 + r;
            t3[(gbase + row) * 32 + col] = f2bf(dtl[row] * acc[r]);
        }
    }
}

// ========= agg3 + pool (gsum) + bf16 mirror ================================
__global__ __launch_bounds__(256) void agg3_pool(const unsigned short* __restrict__ t3,
                                                 const int* __restrict__ offs_,
                                                 const int* __restrict__ esrc_,
                                                 const float* __restrict__ dinv_,
                                                 const float* __restrict__ b,
                                                 float* __restrict__ out,
                                                 unsigned short* __restrict__ outbf,
                                                 float* __restrict__ gsum, int N, int E) {
    int g = blockIdx.y;
    const unsigned short* hp = t3 + (size_t)(g ? N : 0) * 32;
    const int* offs = offs_ + g * (N + 1);
    const int* esrc = esrc_ + (size_t)g * E;
    const float* dinv = dinv_ + g * N;
    int fq = (threadIdx.x & 7) * 4;
    int t = blockIdx.x * 32 + threadIdx.x / 8;
    float dt_row = dinv[t];
    float4 v = aggRowBF<32>(hp, offs, esrc, t, fq);
    float4 bb = *(const float4*)&b[fq];
    v.x = fmaf(dt_row, v.x, bb.x); v.y = fmaf(dt_row, v.y, bb.y);
    v.z = fmaf(dt_row, v.z, bb.z); v.w = fmaf(dt_row, v.w, bb.w);
    *(float4*)&out[((size_t)(g * N + t)) * 32 + fq] = v;
    unsigned short r4[4] = {f2bf(v.x), f2bf(v.y), f2bf(v.z), f2bf(v.w)};
    *(uint2*)&outbf[((size_t)(g * N + t)) * 32 + fq] = *(uint2*)r4;
    __shared__ float ls[32];
    if (threadIdx.x < 32) ls[threadIdx.x] = 0.f;
    __syncthreads();
    atomicAdd(&ls[fq + 0], v.x);
    atomicAdd(&ls[fq + 1], v.y);
    atomicAdd(&ls[fq + 2], v.z);
    atomicAdd(&ls[fq + 3], v.w);
    __syncthreads();
    if (threadIdx.x < 32) {
        int rep = blockIdx.x & (GS_REP - 1);
        atomicAdd(&gsum[((g * GS_REP + rep) * 32 + threadIdx.x) * GS_PAD],
                  ls[threadIdx.x]);
    }
}

// ========= simA: sim min/max (blocks < NSIM) + attention pool (rest) ========
__global__ __launch_bounds__(256) void simA(const unsigned short* __restrict__ afbf,
                                            const float* __restrict__ af,
                                            const float* __restrict__ gsum,
                                            const float* __restrict__ Wa,
                                            float* __restrict__ p12,
                                            float2* __restrict__ pbmm, int N, int NSIM) {
    int bid = blockIdx.x;
    int tid = threadIdx.x;
    int lane = tid & 63, wv = tid >> 6;
    if (bid >= NSIM) {
        int pb = bid - NSIM;
        int npg = N / 256;
        int g = pb / npg;
        int r = (pb % npg) * 256 + tid;
        const float* afg = af + (size_t)g * N * 32;
        __shared__ float cm[32], ctxs[32];
        if (tid < 32) {
            float s = 0.f;
#pragma unroll
            for (int rep = 0; rep < GS_REP; ++rep)
                s += gsum[((g * GS_REP + rep) * 32 + tid) * GS_PAD];
            cm[tid] = s / (float)N;
        }
        __syncthreads();
        if (tid < 32) {
            float s = 0.f;
            for (int d = 0; d < 32; ++d) s = fmaf(cm[d], Wa[d * 32 + tid], s);
            ctxs[tid] = tanhf(s);
        }
        __syncthreads();
        float rowv[32];
        const float4* row = (const float4*)(afg + (size_t)r * 32);
        float dot = 0.f;
#pragma unroll
        for (int q = 0; q < 8; ++q) {
            float4 v = row[q];
            rowv[q * 4 + 0] = v.x; rowv[q * 4 + 1] = v.y;
            rowv[q * 4 + 2] = v.z; rowv[q * 4 + 3] = v.w;
            dot = fmaf(v.x, ctxs[q * 4 + 0], dot);
            dot = fmaf(v.y, ctxs[q * 4 + 1], dot);
            dot = fmaf(v.z, ctxs[q * 4 + 2], dot);
            dot = fmaf(v.w, ctxs[q * 4 + 3], dot);
        }
        float att = 1.f / (1.f + expf(-dot));
        __shared__ float wsum[4][32];
#pragma unroll
        for (int f = 0; f < 32; ++f) {
            float v = att * rowv[f];
#pragma unroll
            for (int off = 1; off < 64; off <<= 1) v += __shfl_xor(v, off);
            if (lane == 0) wsum[wv][f] = v;
        }
        __syncthreads();
        if (tid < 32) {
            float s = wsum[0][tid] + wsum[1][tid] + wsum[2][tid] + wsum[3][tid];
            atomicAdd(&p12[g * 32 + tid], s);
        }
        return;
    }
    const unsigned short* a1 = afbf;
    const unsigned short* a2 = afbf + (size_t)N * 32;
    int nb = N >> 7;
    int nchunk = nb / SIM_CHUNK;
    int by = bid / nchunk;
    int ch = bid % nchunk;
    int r16 = lane & 15, kg = (lane >> 4) << 3;
    const unsigned short* arow = a1 + ((size_t)(by * 128 + (wv >> 1) * 64 + r16)) * 32 + kg;
    bf16x8 afr[4];
#pragma unroll
    for (int m = 0; m < 4; ++m) afr[m] = *(const bf16x8*)(arow + m * 16 * 32);
    float mn = 1e30f, mx = -1e30f;
#pragma unroll
    for (int t = 0; t < SIM_CHUNK; ++t) {
        int bx = ch * SIM_CHUNK + t;
        const unsigned short* brow =
            a2 + ((size_t)(bx * 128 + (wv & 1) * 64 + r16)) * 32 + kg;
        bf16x8 bfr[4];
#pragma unroll
        for (int n = 0; n < 4; ++n) bfr[n] = *(const bf16x8*)(brow + n * 16 * 32);
        f32x4 zero = {0.f, 0.f, 0.f, 0.f};
        f32x4 acc[4][4];
#pragma unroll
        for (int m = 0; m < 4; ++m)
#pragma unroll
            for (int n = 0; n < 4; ++n)
                acc[m][n] =
                    __builtin_amdgcn_mfma_f32_16x16x32_bf16(afr[m], bfr[n], zero, 0, 0, 0);
#pragma unroll
        for (int m = 0; m < 4; ++m)
#pragma unroll
            for (int n = 0; n < 4; ++n)
#pragma unroll
                for (int e = 0; e < 4; ++e) {
                    float v = acc[m][n][e];
                    mn = fminf(mn, v);
                    mx = fmaxf(mx, v);
                }
    }
#pragma unroll
    for (int off = 1; off < 64; off <<= 1) {
        mn = fminf(mn, __shfl_xor(mn, off));
        mx = fmaxf(mx, __shfl_xor(mx, off));
    }
    __shared__ float wmn[4], wmx[4];
    if (lane == 0) { wmn[wv] = mn; wmx[wv] = mx; }
    __syncthreads();
    if (tid == 0) {
        float bmn = fminf(fminf(wmn[0], wmn[1]), fminf(wmn[2], wmn[3]));
        float bmx = fmaxf(fmaxf(wmx[0], wmx[1]), fmaxf(wmx[2], wmx[3]));
        pbmm[bid] = make_float2(bmn, bmx);
    }
}

// ========= simB: histogram (pack 8-bit, flush to 16-bit every 2 tiles) ======
__global__ __launch_bounds__(256) void simB(const unsigned short* __restrict__ a1,
                                            const unsigned short* __restrict__ a2,
                                            int N, int nblk,
                                            const float2* __restrict__ pbmm,
                                            unsigned* __restrict__ pbhist) {
    int nb = N >> 7;
    int nchunk = nb / SIM_CHUNK;
    int by = blockIdx.x / nchunk;
    int ch = blockIdx.x % nchunk;
    int w = threadIdx.x >> 6, lane = threadIdx.x & 63;
    int r16 = lane & 15, kg = (lane >> 4) << 3;
    __shared__ unsigned hs[16];
    __shared__ float mnmx[2];
    if (threadIdx.x < 16) hs[threadIdx.x] = 0;
    {
        float mn2 = 1e30f, mx2 = -1e30f;
        for (int i = threadIdx.x; i < nblk; i += 256) {
            float2 vv = pbmm[i];
            mn2 = fminf(mn2, vv.x);
            mx2 = fmaxf(mx2, vv.y);
        }
#pragma unroll
        for (int off = 1; off < 64; off <<= 1) {
            mn2 = fminf(mn2, __shfl_xor(mn2, off));
            mx2 = fmaxf(mx2, __shfl_xor(mx2, off));
        }
        __shared__ float wmn2[4], wmx2[4];
        if (lane == 0) { wmn2[w] = mn2; wmx2[w] = mx2; }
        __syncthreads();
        if (threadIdx.x == 0) {
            mnmx[0] = fminf(fminf(wmn2[0], wmn2[1]), fminf(wmn2[2], wmn2[3]));
            mnmx[1] = fmaxf(fmaxf(wmx2[0], wmx2[1]), fmaxf(wmx2[2], wmx2[3]));
        }
        __syncthreads();
    }
    float mnv = mnmx[0], mxv = mnmx[1];
    float width = (mxv > mnv) ? (mxv - mnv) : 1.0f;
    float scale = 16.0f / width;
    float nbias = -mnv * scale;
    const unsigned short* arow = a1 + ((size_t)(by * 128 + (w >> 1) * 64 + r16)) * 32 + kg;
    bf16x8 afr[4];
#pragma unroll
    for (int m = 0; m < 4; ++m) afr[m] = *(const bf16x8*)(arow + m * 16 * 32);
    unsigned hh[8] = {0u, 0u, 0u, 0u, 0u, 0u, 0u, 0u};
#pragma unroll
    for (int half = 0; half < SIM_CHUNK / 2; ++half) {
        unsigned h4_0 = 0, h4_1 = 0, h4_2 = 0, h4_3 = 0;
#pragma unroll
        for (int t = 0; t < 2; ++t) {
            int bx = ch * SIM_CHUNK + half * 2 + t;
            const unsigned short* brow =
                a2 + ((size_t)(bx * 128 + (w & 1) * 64 + r16)) * 32 + kg;
            bf16x8 bfr[4];
#pragma unroll
            for (int n = 0; n < 4; ++n) bfr[n] = *(const bf16x8*)(brow + n * 16 * 32);
            f32x4 zero = {0.f, 0.f, 0.f, 0.f};
            f32x4 acc[4][4];
#pragma unroll
            for (int m = 0; m < 4; ++m)
#pragma unroll
                for (int n = 0; n < 4; ++n)
                    acc[m][n] = __builtin_amdgcn_mfma_f32_16x16x32_bf16(afr[m], bfr[n],
                                                                        zero, 0, 0, 0);
#pragma unroll
            for (int m = 0; m < 4; ++m)
#pragma unroll
                for (int n = 0; n < 4; ++n)
#pragma unroll
                    for (int e = 0; e < 4; ++e) {
                        float v = acc[m][n][e];
                        int bin = (int)fmaf(v, scale, nbias);
                        bin = bin < 0 ? 0 : (bin > 15 ? 15 : bin);
                        unsigned wbit = 1u << ((bin & 3) << 3);
                        int hi = bin >> 2;
                        h4_0 += (hi == 0) ? wbit : 0u;
                        h4_1 += (hi == 1) ? wbit : 0u;
                        h4_2 += (hi == 2) ? wbit : 0u;
                        h4_3 += (hi == 3) ? wbit : 0u;
                    }
        }
        hh[0] += h4_0 & 0x00FF00FFu; hh[1] += (h4_0 >> 8) & 0x00FF00FFu;
        hh[2] += h4_1 & 0x00FF00FFu; hh[3] += (h4_1 >> 8) & 0x00FF00FFu;
        hh[4] += h4_2 & 0x00FF00FFu; hh[5] += (h4_2 >> 8) & 0x00FF00FFu;
        hh[6] += h4_3 & 0x00FF00FFu; hh[7] += (h4_3 >> 8) & 0x00FF00FFu;
    }
#pragma unroll
    for (int off = 1; off < 64; off <<= 1) {
#pragma unroll
        for (int q = 0; q < 8; ++q) hh[q] += (unsigned)__shfl_xor((int)hh[q], off);
    }
    __syncthreads();
    if (lane < 16) {
        int q = lane >> 2, r = lane & 3;
        unsigned word = hh[2 * q + (r & 1)];
        unsigned val = (r < 2) ? (word & 0xFFFFu) : (word >> 16);
        atomicAdd(&hs[lane], val);
    }
    __syncthreads();
    if (threadIdx.x < 16)
        pbhist[(size_t)blockIdx.x * 16 + threadIdx.x] = hs[threadIdx.x];
}

// ========= hist reduce + NTN + MLP head ====================================
__global__ __launch_bounds__(256) void ntn_final(
    const float* __restrict__ p12, const float* __restrict__ Wt,
    const float* __restrict__ V, const float* __restrict__ bt,
    const unsigned* __restrict__ pbhist, int nblk,
    const float* __restrict__ fc1W, const float* __restrict__ fc1b,
    const float* __restrict__ fc2W, const float* __restrict__ fc2b,
    const float* __restrict__ fc3W, const float* __restrict__ fc3b,
    const float* __restrict__ scW, const float* __restrict__ scb,
    const float* __restrict__ avg_v, float* __restrict__ out) {
    __shared__ float p1l[32], p2l[32];
    __shared__ float scp[16][17];
    __shared__ unsigned hs[16];
    __shared__ float sc[16];
    __shared__ float sfeat[32];
    __shared__ float h1s[16];
    int t = threadIdx.x;
    if (t < 16) hs[t] = 0;
    if (t < 32) p1l[t] = p12[t];
    else if (t < 64) p2l[t - 32] = p12[t];
    __syncthreads();
    {
        const uint4* pb = (const uint4*)pbhist;
        int total = nblk * 4;
        uint4 a = {0u, 0u, 0u, 0u};
        for (int i = t; i < total; i += 256) {
            uint4 v = pb[i];
            a.x += v.x; a.y += v.y; a.z += v.z; a.w += v.w;
        }
#pragma unroll
        for (int off = 4; off < 64; off <<= 1) {
            a.x += (unsigned)__shfl_xor((int)a.x, off);
            a.y += (unsigned)__shfl_xor((int)a.y, off);
            a.z += (unsigned)__shfl_xor((int)a.z, off);
            a.w += (unsigned)__shfl_xor((int)a.w, off);
        }
        int lane = t & 63;
        if (lane < 4) {
            atomicAdd(&hs[lane * 4 + 0], a.x);
            atomicAdd(&hs[lane * 4 + 1], a.y);
            atomicAdd(&hs[lane * 4 + 2], a.z);
            atomicAdd(&hs[lane * 4 + 3], a.w);
        }
    }
    {
        int k = t & 15, dp = t >> 4;
        float s = 0.f;
#pragma unroll
        for (int dd = 0; dd < 2; ++dd) {
            int d = dp * 2 + dd;
            float a = p1l[d];
            for (int e = 0; e < 32; ++e)
                s = fmaf(a * p2l[e], Wt[(d * 32 + e) * 16 + k], s);
        }
        scp[dp][k] = s;
    }
    __syncthreads();
    if (t < 16) {
        float s = 0.f;
#pragma unroll
        for (int dp = 0; dp < 16; ++dp) s += scp[dp][t];
        float bl = 0.f;
        for (int m = 0; m < 32; ++m) bl = fmaf(V[t * 64 + m], p1l[m], bl);
        for (int m = 0; m < 32; ++m) bl = fmaf(V[t * 64 + 32 + m], p2l[m], bl);
        sc[t] = fmaxf(s + bl + bt[t], 0.f);
    }
    __syncthreads();
    if (t < 16) sfeat[t] = sc[t];
    if (t == 16) {
        unsigned tot = 0;
        for (int b = 0; b < 16; ++b) tot += hs[b];
        float ftot = (float)tot;
        for (int b = 0; b < 16; ++b) sfeat[16 + b] = (float)hs[b] / ftot;
    }
    __syncthreads();
    if (t < 16) {
        float a = fc1b[t];
        for (int m = 0; m < 32; ++m) a = fmaf(sfeat[m], fc1W[m * 16 + t], a);
        h1s[t] = fmaxf(a, 0.f);
    }
    __syncthreads();
    if (t != 0) return;
    float h2[8];
    for (int r = 0; r < 8; ++r) {
        float a = fc2b[r];
        for (int m = 0; m < 16; ++m) a = fmaf(h1s[m], fc2W[m * 8 + r], a);
        h2[r] = fmaxf(a, 0.f);
    }
    float h3[4];
    for (int r = 0; r < 4; ++r) {
        float a = fc3b[r];
        for (int m = 0; m < 8; ++m) a = fmaf(h2[m], fc3W[m * 4 + r], a);
        h3[r] = fmaxf(a, 0.f);
    }
    float z = scb[0];
    for (int m = 0; m < 4; ++m) z = fmaf(h3[m], scW[m], z);
    float sig = 1.f / (1.f + expf(-z));
    out[0] = sig;
    out[1] = -logf(sig) * avg_v[0];
}

// ---------------------------------------------------------------------------
extern "C" void kernel_launch(void* const* d_in, const int* in_sizes, int n_in,
                              void* d_out, int out_size, void* d_ws, size_t ws_size,
                              hipStream_t stream) {
    (void)n_in; (void)out_size; (void)ws_size;
    const int* ei1 = (const int*)d_in[0];
    const int* ei2 = (const int*)d_in[1];
    const float* feat1 = (const float*)d_in[2];
    const float* feat2 = (const float*)d_in[3];
    const float* avg_v = (const float*)d_in[4];
    const float* W1 = (const float*)d_in[5];
    const float* b1 = (const float*)d_in[6];
    const float* W2 = (const float*)d_in[7];
    const float* b2 = (const float*)d_in[8];
    const float* W3 = (const float*)d_in[9];
    const float* b3 = (const float*)d_in[10];
    const float* Wa = (const float*)d_in[11];
    const float* Wt = (const float*)d_in[12];
    const float* V = (const float*)d_in[13];
    const float* bt = (const float*)d_in[14];
    const float* fc1W = (const float*)d_in[15];
    const float* fc1b = (const float*)d_in[16];
    const float* fc2W = (const float*)d_in[17];
    const float* fc2b = (const float*)d_in[18];
    const float* fc3W = (const float*)d_in[19];
    const float* fc3b = (const float*)d_in[20];
    const float* scW = (const float*)d_in[21];
    const float* scb = (const float*)d_in[22];

    const int E = in_sizes[0] / 2;
    const int N = in_sizes[2] / 64;
    const int nb = N / 128;
    const int nchunk = nb / SIM_CHUNK;
    const int NSIM = nb * nchunk;
    const int E4 = E / 4;

    // ---- workspace layout ----
    char* w = (char*)d_ws;
    size_t off = 0;
    auto take = [&](size_t bytes) -> char* {
        char* p = w + off;
        off = (off + bytes + 255) & ~(size_t)255;
        return p;
    };
    float* gsum = (float*)take((size_t)2 * GS_REP * 32 * GS_PAD * 4);  // zero start
    float* p12 = (float*)take(64 * 4);
    int* cnt = (int*)take((size_t)2 * N * 4);                          // zero end
    float* af = (float*)take((size_t)2 * N * 32 * 4);
    unsigned short* afbf = (unsigned short*)take((size_t)2 * N * 32 * 2);
    float2* pbmm = (float2*)take((size_t)NSIM * 8);
    unsigned* pbhist = (unsigned*)take((size_t)NSIM * 16 * 4);
    float* dinv = (float*)take((size_t)2 * N * 4);
    int* offs = (int*)take((size_t)2 * (N + 1) * 4);
    int* cursor = (int*)take((size_t)2 * N * 4);
    int* esrc = (int*)take((size_t)2 * E * 4);
    unsigned short* xs = (unsigned short*)take((size_t)2 * N * 64 * 2);
    unsigned short* t1 = (unsigned short*)take((size_t)2 * N * 64 * 2);
    unsigned short* t3 = (unsigned short*)take((size_t)2 * N * 32 * 2);
    unsigned short* W1t = (unsigned short*)take(128 * 64 * 2);
    unsigned short* W2t = (unsigned short*)take(64 * 128 * 2);
    unsigned short* W3t = (unsigned short*)take(32 * 64 * 2);

    size_t zbytes = ((char*)cnt + (size_t)2 * N * 4) - (char*)gsum;
    int zn4 = (int)(zbytes / 16);

    // ---- CSR build + prep ----
    zero_prep<<<(zn4 + 255) / 256 + 3, 256, 0, stream>>>((float4*)gsum, zn4, W1, W2, W3,
                                                         W1t, W2t, W3t);
    count_tgt<<<dim3((E4 + 255) / 256, 2), 256, 0, stream>>>(ei1 + E, ei2 + E, cnt, N, E4);
    scan_xscale<<<2 + (2 * N * 16 + 1023) / 1024, 1024, 0, stream>>>(
        cnt, offs, cursor, dinv, feat1, feat2, xs, N);
    scatter_src<<<dim3((E4 + 255) / 256, 2), 256, 0, stream>>>(ei1, ei2, ei1 + E, ei2 + E,
                                                               cursor, esrc, N, E, E4);

    // ---- fused GCN pipeline ----
    fusedA<<<dim3(N / 16, 2), 256, 0, stream>>>(xs, W1t, b1, W2t, t1, offs, esrc, dinv,
                                                N, E);
    fusedB<<<dim3(N / 16, 2), 256, 0, stream>>>(t1, b2, W3t, t3, offs, esrc, dinv, N, E);
    agg3_pool<<<dim3(N / 32, 2), 256, 0, stream>>>(t3, offs, esrc, dinv, b3, af, afbf,
                                                   gsum, N, E);
    simA<<<NSIM + (N / 256) * 2, 256, 0, stream>>>(afbf, af, gsum, Wa, p12, pbmm, N, NSIM);
    simB<<<NSIM, 256, 0, stream>>>(afbf, afbf + (size_t)N * 32, N, NSIM, pbmm, pbhist);
    ntn_final<<<1, 256, 0, stream>>>(p12, Wt, V, bt, pbhist, NSIM, fc1W, fc1b, fc2W, fc2b,
                                     fc3W, fc3b, scW, scb, avg_v, (float*)d_out);
}